// Round 1
// baseline (1343.622 us; speedup 1.0000x reference)
//
#include <hip/hip_runtime.h>

constexpr int H    = 64;     // hidden/out features
constexpr int FIN  = 256;    // input features
constexpr int NIT  = 20;     // fixed-point iterations
// ALPHA = 0.1 folded into benc kernel

// ---------------- Wc = W_enc @ W_bias  [FIN x H] ----------------
__global__ __launch_bounds__(256) void wc_kernel(const float* __restrict__ We,
                                                 const float* __restrict__ Wb,
                                                 float* __restrict__ Wc) {
    __shared__ float wb[H * H];
    for (int i = threadIdx.x; i < H * H / 4; i += 256)
        reinterpret_cast<float4*>(wb)[i] = reinterpret_cast<const float4*>(Wb)[i];
    __syncthreads();
    int idx = blockIdx.x * 256 + threadIdx.x;    // 0 .. FIN*H-1
    int i = idx >> 6, j = idx & 63;
    float acc = 0.f;
#pragma unroll 8
    for (int k = 0; k < H; ++k) acc += We[i * H + k] * wb[k * H + j];
    Wc[i * H + j] = acc;
}

// ------------- b = 0.1 * x @ Wc ; u0 = 0 ; uh0 = -b -------------
__global__ __launch_bounds__(256) void benc_kernel(const float* __restrict__ x,
                                                   const float* __restrict__ Wc,
                                                   float* __restrict__ b,
                                                   float* __restrict__ u0,
                                                   float* __restrict__ uh0, int N) {
    __shared__ float wls[FIN * H];   // 64 KB
    __shared__ float xs[4][FIN];     // 4 KB
    for (int i = threadIdx.x; i < FIN * H / 4; i += 256)
        reinterpret_cast<float4*>(wls)[i] = reinterpret_cast<const float4*>(Wc)[i];
    int groups = (N + 3) / 4;
    for (int g = blockIdx.x; g < groups; g += gridDim.x) {
        __syncthreads();   // Wc visible on first pass; xs safe to overwrite on later passes
        int n0 = g * 4;
        {   // stage 4 rows of x as float4 (256 float4s, one per thread)
            int i = threadIdx.x;
            int r = i >> 6, c = i & 63;
            int n = n0 + r;
            float4 v = (n < N) ? reinterpret_cast<const float4*>(x + (size_t)n * FIN)[c]
                               : make_float4(0.f, 0.f, 0.f, 0.f);
            reinterpret_cast<float4*>(&xs[r][0])[c] = v;
        }
        __syncthreads();
        int r = threadIdx.x >> 6, j = threadIdx.x & 63;
        int n = n0 + r;
        if (n < N) {
            float acc = 0.f;
#pragma unroll 8
            for (int k = 0; k < FIN; ++k) acc += xs[r][k] * wls[k * H + j];
            float bv = 0.1f * acc;
            b[(size_t)n * H + j]   = bv;
            u0[(size_t)n * H + j]  = 0.f;
            uh0[(size_t)n * H + j] = -bv;
        }
    }
}

// ---------------- CSR build ----------------
__global__ __launch_bounds__(256) void hist_kernel(const int* __restrict__ ei, int* __restrict__ cnt, int E) {
    int e = blockIdx.x * 256 + threadIdx.x;
    if (e < E) atomicAdd(&cnt[ei[E + e]], 1);
}

__global__ __launch_bounds__(1024) void scan1_kernel(const int* __restrict__ cnt,
                                                     int* __restrict__ excl,
                                                     int* __restrict__ partials, int n) {
    __shared__ int sd[1024];
    int i = blockIdx.x * 1024 + threadIdx.x;
    sd[threadIdx.x] = (i < n) ? cnt[i] : 0;
    __syncthreads();
    for (int off = 1; off < 1024; off <<= 1) {
        int t = (threadIdx.x >= (unsigned)off) ? sd[threadIdx.x - off] : 0;
        __syncthreads();
        sd[threadIdx.x] += t;
        __syncthreads();
    }
    if (i < n) excl[i + 1] = sd[threadIdx.x];
    if (threadIdx.x == 1023) partials[blockIdx.x] = sd[1023];
}

__global__ void scan2_kernel(int* __restrict__ partials, int nb) {
    int lane = threadIdx.x;               // single wave of 64, nb <= 64
    int v = (lane < nb) ? partials[lane] : 0;
    for (int off = 1; off < 64; off <<= 1) {
        int t = __shfl_up(v, off);
        if (lane >= off) v += t;
    }
    int ex = __shfl_up(v, 1);
    if (lane == 0) ex = 0;
    if (lane < nb) partials[lane] = ex;
}

__global__ __launch_bounds__(1024) void scan3_kernel(int* __restrict__ excl,
                                                     const int* __restrict__ partials, int n) {
    int i = blockIdx.x * 1024 + threadIdx.x;
    if (i < n) excl[i + 1] += partials[blockIdx.x];
    if (i == 0) excl[0] = 0;
}

__global__ __launch_bounds__(256) void copycur_kernel(const int* __restrict__ rs, int* __restrict__ cur, int n) {
    int i = blockIdx.x * 256 + threadIdx.x;
    if (i < n) cur[i] = rs[i];
}

__global__ __launch_bounds__(256) void scatter_kernel(const int* __restrict__ ei,
                                                      const float* __restrict__ ew,
                                                      int* __restrict__ cur,
                                                      int* __restrict__ csr_src,
                                                      float* __restrict__ csr_w, int E) {
    int e = blockIdx.x * 256 + threadIdx.x;
    if (e < E) {
        int d = ei[E + e];
        int pos = atomicAdd(&cur[d], 1);
        csr_src[pos] = ei[e];
        csr_w[pos]   = ew[e];
    }
}

// ---------------- one Peaceman-Rachford step (fused) ----------------
// un        = 2*V(uh) - 2*relu(u) + u
// uh_next   = 2*relu(un) - un - b
__global__ __launch_bounds__(256) void step_kernel(const float* __restrict__ u,
                                                   const float* __restrict__ uh,
                                                   const float* __restrict__ b,
                                                   const int* __restrict__ row_start,
                                                   const int* __restrict__ csr_src,
                                                   const float* __restrict__ csr_w,
                                                   float* __restrict__ u_next,
                                                   float* __restrict__ uh_next, int N) {
    int node = blockIdx.x * 4 + (threadIdx.x >> 6);
    int lane = threadIdx.x & 63;
    if (node >= N) return;
    int e0 = row_start[node];
    int deg = row_start[node + 1] - e0;
    float s = 0.f;
    for (int base = 0; base < deg; base += 64) {
        int idx = base + lane;
        int src = 0; float w = 0.f;
        if (idx < deg) { src = csr_src[e0 + idx]; w = csr_w[e0 + idx]; }
        int cnt = min(64, deg - base);
        for (int t = 0; t < cnt; ++t) {
            int   st = __shfl(src, t);
            float wt = __shfl(w, t);
            s += wt * uh[(size_t)st * H + lane];
        }
    }
    size_t o = (size_t)node * H + lane;
    float uv = u[o];
    float bv = b[o];
    float r  = fmaxf(uv, 0.f);
    float un = 2.f * s - 2.f * r + uv;
    float rn = fmaxf(un, 0.f);
    u_next[o]  = un;
    uh_next[o] = 2.f * rn - un - bv;
}

// ---------------- out = relu(u) @ W_dec ----------------
__global__ __launch_bounds__(256) void dec_kernel(const float* __restrict__ u,
                                                  const float* __restrict__ Wd,
                                                  float* __restrict__ out, int N) {
    __shared__ float wls[H * H];   // 16 KB
    __shared__ float rs[4][H];
    for (int i = threadIdx.x; i < H * H / 4; i += 256)
        reinterpret_cast<float4*>(wls)[i] = reinterpret_cast<const float4*>(Wd)[i];
    int groups = (N + 3) / 4;
    for (int g = blockIdx.x; g < groups; g += gridDim.x) {
        __syncthreads();
        int r = threadIdx.x >> 6, j = threadIdx.x & 63;
        int n = g * 4 + r;
        if (n < N) rs[r][j] = fmaxf(u[(size_t)n * H + j], 0.f);
        __syncthreads();
        if (n < N) {
            float acc = 0.f;
#pragma unroll 8
            for (int k = 0; k < H; ++k) acc += rs[r][k] * wls[k * H + j];
            out[(size_t)n * H + j] = acc;
        }
    }
}

extern "C" void kernel_launch(void* const* d_in, const int* in_sizes, int n_in,
                              void* d_out, int out_size, void* d_ws, size_t ws_size,
                              hipStream_t stream) {
    const float* x  = (const float*)d_in[0];
    const int*   ei = (const int*)d_in[1];
    const float* ew = (const float*)d_in[2];
    const float* We = (const float*)d_in[3];
    const float* Wb = (const float*)d_in[4];
    const float* Wd = (const float*)d_in[5];
    float* out = (float*)d_out;

    const int N = in_sizes[0] / FIN;
    const int E = in_sizes[2];

    char* ws = (char*)d_ws;
    size_t off = 0;
    auto alloc = [&](size_t bytes) -> void* {
        void* p = ws + off;
        off = (off + bytes + 255) & ~(size_t)255;
        return p;
    };
    const size_t nodeb = (size_t)N * H * sizeof(float);
    float* b    = (float*)alloc(nodeb);
    float* ua   = (float*)alloc(nodeb);
    float* ub   = (float*)alloc(nodeb);
    float* uha  = (float*)alloc(nodeb);
    float* uhb  = (float*)alloc(nodeb);
    float* Wc   = (float*)alloc((size_t)FIN * H * sizeof(float));
    int*   rsrt = (int*)alloc((size_t)(N + 1) * sizeof(int));   // row_start
    int*   cnt  = (int*)alloc((size_t)N * sizeof(int));         // counts, then cursor
    int*   part = (int*)alloc(256 * sizeof(int));
    int*   csrc = (int*)alloc((size_t)E * sizeof(int));
    float* cw   = (float*)alloc((size_t)E * sizeof(float));

    const int nb = (N + 1023) / 1024;

    // CSR build
    hipMemsetAsync(cnt, 0, (size_t)N * sizeof(int), stream);
    hist_kernel<<<(E + 255) / 256, 256, 0, stream>>>(ei, cnt, E);
    scan1_kernel<<<nb, 1024, 0, stream>>>(cnt, rsrt, part, N);
    scan2_kernel<<<1, 64, 0, stream>>>(part, nb);
    scan3_kernel<<<nb, 1024, 0, stream>>>(rsrt, part, N);
    copycur_kernel<<<(N + 255) / 256, 256, 0, stream>>>(rsrt, cnt, N);
    scatter_kernel<<<(E + 255) / 256, 256, 0, stream>>>(ei, ew, cnt, csrc, cw, E);

    // encoder path
    wc_kernel<<<FIN * H / 256, 256, 0, stream>>>(We, Wb, Wc);
    benc_kernel<<<1024, 256, 0, stream>>>(x, Wc, b, ua, uha, N);

    // fixed-point iterations (ping-pong)
    float *ucur = ua, *unext = ub, *uhcur = uha, *uhnext = uhb;
    for (int it = 0; it < NIT; ++it) {
        step_kernel<<<(N + 3) / 4, 256, 0, stream>>>(ucur, uhcur, b, rsrt, csrc, cw,
                                                     unext, uhnext, N);
        float* t;
        t = ucur;  ucur  = unext;  unext  = t;
        t = uhcur; uhcur = uhnext; uhnext = t;
    }

    // decoder
    dec_kernel<<<1024, 256, 0, stream>>>(ucur, Wd, out, N);
}

// Round 2
// 846.762 us; speedup vs baseline: 1.5868x; 1.5868x over previous
//
#include <hip/hip_runtime.h>

constexpr int H    = 64;     // hidden/out features
constexpr int FIN  = 256;    // input features
constexpr int NIT  = 20;     // fixed-point iterations
// ALPHA = 0.1 folded into benc kernel

// ---------------- Wc = W_enc @ W_bias  [FIN x H] ----------------
__global__ __launch_bounds__(256) void wc_kernel(const float* __restrict__ We,
                                                 const float* __restrict__ Wb,
                                                 float* __restrict__ Wc) {
    __shared__ float wb[H * H];
    for (int i = threadIdx.x; i < H * H / 4; i += 256)
        reinterpret_cast<float4*>(wb)[i] = reinterpret_cast<const float4*>(Wb)[i];
    __syncthreads();
    int idx = blockIdx.x * 256 + threadIdx.x;    // 0 .. FIN*H-1
    int i = idx >> 6, j = idx & 63;
    float acc = 0.f;
#pragma unroll 8
    for (int k = 0; k < H; ++k) acc += We[i * H + k] * wb[k * H + j];
    Wc[i * H + j] = acc;
}

// ------------- b = 0.1 * x @ Wc  (register-tiled 4x4) -------------
// block = 256 threads handles 64 rows x 64 cols; thread (tr,tc) owns 4x4 tile
__global__ __launch_bounds__(256) void benc_kernel(const float* __restrict__ x,
                                                   const float* __restrict__ Wc,
                                                   float* __restrict__ bout, int N) {
    __shared__ float xs[64][68];    // transposed x chunk: xs[k][r]
    __shared__ float wls[64][64];   // Wc chunk: wls[k][j]
    const int t  = threadIdx.x;
    const int tr = t >> 4;          // 0..15 row-group
    const int tc = t & 15;          // 0..15 col-group
    const int n0 = blockIdx.x * 64;

    float4 acc0 = {0,0,0,0}, acc1 = {0,0,0,0}, acc2 = {0,0,0,0}, acc3 = {0,0,0,0};

    for (int kc = 0; kc < FIN; kc += 64) {
        __syncthreads();
        // stage Wc chunk (4096 floats contiguous)
        for (int i = t; i < 64 * 64 / 4; i += 256)
            reinterpret_cast<float4*>(&wls[0][0])[i] =
                reinterpret_cast<const float4*>(Wc + (size_t)kc * 64)[i];
        // stage x chunk transposed
        for (int rp = 0; rp < 64; rp += 16) {
            int r = rp + (t >> 4);
            int c = (t & 15) * 4;
            int n = n0 + r; if (n >= N) n = N - 1;
            float4 v = reinterpret_cast<const float4*>(x + (size_t)n * FIN + kc)[t & 15];
            xs[c + 0][r] = v.x; xs[c + 1][r] = v.y; xs[c + 2][r] = v.z; xs[c + 3][r] = v.w;
        }
        __syncthreads();
#pragma unroll 8
        for (int k = 0; k < 64; ++k) {
            float4 xv = *reinterpret_cast<const float4*>(&xs[k][tr * 4]);
            float4 wv = *reinterpret_cast<const float4*>(&wls[k][tc * 4]);
            acc0.x = fmaf(xv.x, wv.x, acc0.x); acc0.y = fmaf(xv.x, wv.y, acc0.y);
            acc0.z = fmaf(xv.x, wv.z, acc0.z); acc0.w = fmaf(xv.x, wv.w, acc0.w);
            acc1.x = fmaf(xv.y, wv.x, acc1.x); acc1.y = fmaf(xv.y, wv.y, acc1.y);
            acc1.z = fmaf(xv.y, wv.z, acc1.z); acc1.w = fmaf(xv.y, wv.w, acc1.w);
            acc2.x = fmaf(xv.z, wv.x, acc2.x); acc2.y = fmaf(xv.z, wv.y, acc2.y);
            acc2.z = fmaf(xv.z, wv.z, acc2.z); acc2.w = fmaf(xv.z, wv.w, acc2.w);
            acc3.x = fmaf(xv.w, wv.x, acc3.x); acc3.y = fmaf(xv.w, wv.y, acc3.y);
            acc3.z = fmaf(xv.w, wv.z, acc3.z); acc3.w = fmaf(xv.w, wv.w, acc3.w);
        }
    }
    float4 o;
    int n;
    n = n0 + tr * 4 + 0;
    if (n < N) { o.x = 0.1f*acc0.x; o.y = 0.1f*acc0.y; o.z = 0.1f*acc0.z; o.w = 0.1f*acc0.w;
                 reinterpret_cast<float4*>(bout + (size_t)n * 64)[tc] = o; }
    n = n0 + tr * 4 + 1;
    if (n < N) { o.x = 0.1f*acc1.x; o.y = 0.1f*acc1.y; o.z = 0.1f*acc1.z; o.w = 0.1f*acc1.w;
                 reinterpret_cast<float4*>(bout + (size_t)n * 64)[tc] = o; }
    n = n0 + tr * 4 + 2;
    if (n < N) { o.x = 0.1f*acc2.x; o.y = 0.1f*acc2.y; o.z = 0.1f*acc2.z; o.w = 0.1f*acc2.w;
                 reinterpret_cast<float4*>(bout + (size_t)n * 64)[tc] = o; }
    n = n0 + tr * 4 + 3;
    if (n < N) { o.x = 0.1f*acc3.x; o.y = 0.1f*acc3.y; o.z = 0.1f*acc3.z; o.w = 0.1f*acc3.w;
                 reinterpret_cast<float4*>(bout + (size_t)n * 64)[tc] = o; }
}

// ---------------- CSR build ----------------
__global__ __launch_bounds__(256) void hist_kernel(const int* __restrict__ ei, int* __restrict__ cnt, int E) {
    int e = blockIdx.x * 256 + threadIdx.x;
    if (e < E) atomicAdd(&cnt[ei[E + e]], 1);
}

__global__ __launch_bounds__(1024) void scan1_kernel(const int* __restrict__ cnt,
                                                     int* __restrict__ excl,
                                                     int* __restrict__ partials, int n) {
    __shared__ int sd[1024];
    int i = blockIdx.x * 1024 + threadIdx.x;
    sd[threadIdx.x] = (i < n) ? cnt[i] : 0;
    __syncthreads();
    for (int off = 1; off < 1024; off <<= 1) {
        int t = (threadIdx.x >= (unsigned)off) ? sd[threadIdx.x - off] : 0;
        __syncthreads();
        sd[threadIdx.x] += t;
        __syncthreads();
    }
    if (i < n) excl[i + 1] = sd[threadIdx.x];
    if (threadIdx.x == 1023) partials[blockIdx.x] = sd[1023];
}

__global__ void scan2_kernel(int* __restrict__ partials, int nb) {
    int lane = threadIdx.x;               // single wave of 64, nb <= 64
    int v = (lane < nb) ? partials[lane] : 0;
    for (int off = 1; off < 64; off <<= 1) {
        int t = __shfl_up(v, off);
        if (lane >= off) v += t;
    }
    int ex = __shfl_up(v, 1);
    if (lane == 0) ex = 0;
    if (lane < nb) partials[lane] = ex;
}

__global__ __launch_bounds__(1024) void scan3_kernel(int* __restrict__ excl,
                                                     const int* __restrict__ partials, int n) {
    int i = blockIdx.x * 1024 + threadIdx.x;
    if (i < n) excl[i + 1] += partials[blockIdx.x];
    if (i == 0) excl[0] = 0;
}

__global__ __launch_bounds__(256) void copycur_kernel(const int* __restrict__ rs, int* __restrict__ cur, int n) {
    int i = blockIdx.x * 256 + threadIdx.x;
    if (i < n) cur[i] = rs[i];
}

// pack (src, w) into one 8B word at CSR position
__global__ __launch_bounds__(256) void scatter_kernel(const int* __restrict__ ei,
                                                      const float* __restrict__ ew,
                                                      int* __restrict__ cur,
                                                      unsigned long long* __restrict__ epk, int E) {
    int e = blockIdx.x * 256 + threadIdx.x;
    if (e < E) {
        int d = ei[E + e];
        int pos = atomicAdd(&cur[d], 1);
        unsigned long long pk = ((unsigned long long)__float_as_uint(ew[e]) << 32)
                              | (unsigned int)ei[e];
        epk[pos] = pk;
    }
}

// ---------------- one Peaceman-Rachford step (fused) ----------------
// normal:  un = 2*V(uh) - 2*relu(u) + u ;  uh_next = 2*relu(un) - un - b
// first :  gsrc = b, u == 0  =>  un = 2*V(-b) = -2*V(b)
// lane layout: sub = lane>>4 (edge subgroup), fq = lane&15 (feature quad)
__global__ __launch_bounds__(256) void step_kernel(const float4* __restrict__ u,
                                                   const float4* __restrict__ gsrc,
                                                   const float4* __restrict__ b,
                                                   const int* __restrict__ row_start,
                                                   const unsigned long long* __restrict__ epk,
                                                   float4* __restrict__ u_next,
                                                   float4* __restrict__ uh_next,
                                                   int N, int is_first) {
    int node = blockIdx.x * 4 + (threadIdx.x >> 6);
    if (node >= N) return;
    int lane = threadIdx.x & 63;
    int sub  = lane >> 4;
    int fq   = lane & 15;
    int e0 = row_start[node];
    int e1 = row_start[node + 1];

    float4 a0 = {0,0,0,0}, a1 = {0,0,0,0};
    int e = e0 + sub;
    for (; e + 4 < e1; e += 8) {
        unsigned long long p0 = epk[e];
        unsigned long long p1 = epk[e + 4];
        int   s0 = (int)(p0 & 0xffffffffULL);
        int   s1 = (int)(p1 & 0xffffffffULL);
        float w0 = __uint_as_float((unsigned int)(p0 >> 32));
        float w1 = __uint_as_float((unsigned int)(p1 >> 32));
        float4 v0 = gsrc[(size_t)s0 * 16 + fq];
        float4 v1 = gsrc[(size_t)s1 * 16 + fq];
        a0.x = fmaf(w0, v0.x, a0.x); a0.y = fmaf(w0, v0.y, a0.y);
        a0.z = fmaf(w0, v0.z, a0.z); a0.w = fmaf(w0, v0.w, a0.w);
        a1.x = fmaf(w1, v1.x, a1.x); a1.y = fmaf(w1, v1.y, a1.y);
        a1.z = fmaf(w1, v1.z, a1.z); a1.w = fmaf(w1, v1.w, a1.w);
    }
    if (e < e1) {
        unsigned long long p0 = epk[e];
        int   s0 = (int)(p0 & 0xffffffffULL);
        float w0 = __uint_as_float((unsigned int)(p0 >> 32));
        float4 v0 = gsrc[(size_t)s0 * 16 + fq];
        a0.x = fmaf(w0, v0.x, a0.x); a0.y = fmaf(w0, v0.y, a0.y);
        a0.z = fmaf(w0, v0.z, a0.z); a0.w = fmaf(w0, v0.w, a0.w);
    }
    float4 s;
    s.x = a0.x + a1.x; s.y = a0.y + a1.y; s.z = a0.z + a1.z; s.w = a0.w + a1.w;
    s.x += __shfl_xor(s.x, 16); s.y += __shfl_xor(s.y, 16);
    s.z += __shfl_xor(s.z, 16); s.w += __shfl_xor(s.w, 16);
    s.x += __shfl_xor(s.x, 32); s.y += __shfl_xor(s.y, 32);
    s.z += __shfl_xor(s.z, 32); s.w += __shfl_xor(s.w, 32);

    if (sub == 0) {
        size_t o = (size_t)node * 16 + fq;
        float4 bv = b[o];
        float4 un;
        if (is_first) {
            un.x = -2.f * s.x; un.y = -2.f * s.y; un.z = -2.f * s.z; un.w = -2.f * s.w;
        } else {
            float4 uv = u[o];
            un.x = 2.f * s.x - 2.f * fmaxf(uv.x, 0.f) + uv.x;
            un.y = 2.f * s.y - 2.f * fmaxf(uv.y, 0.f) + uv.y;
            un.z = 2.f * s.z - 2.f * fmaxf(uv.z, 0.f) + uv.z;
            un.w = 2.f * s.w - 2.f * fmaxf(uv.w, 0.f) + uv.w;
        }
        float4 uhn;
        uhn.x = 2.f * fmaxf(un.x, 0.f) - un.x - bv.x;
        uhn.y = 2.f * fmaxf(un.y, 0.f) - un.y - bv.y;
        uhn.z = 2.f * fmaxf(un.z, 0.f) - un.z - bv.z;
        uhn.w = 2.f * fmaxf(un.w, 0.f) - un.w - bv.w;
        u_next[o]  = un;
        uh_next[o] = uhn;
    }
}

// ---------------- out = relu(u) @ W_dec  (register-tiled 4x4) ----------------
__global__ __launch_bounds__(256) void dec_kernel(const float* __restrict__ u,
                                                  const float* __restrict__ Wd,
                                                  float* __restrict__ out, int N) {
    __shared__ float xs[64][68];    // transposed relu(u) chunk
    __shared__ float wls[64][64];
    const int t  = threadIdx.x;
    const int tr = t >> 4;
    const int tc = t & 15;
    const int n0 = blockIdx.x * 64;

    for (int i = t; i < 64 * 64 / 4; i += 256)
        reinterpret_cast<float4*>(&wls[0][0])[i] = reinterpret_cast<const float4*>(Wd)[i];
    for (int rp = 0; rp < 64; rp += 16) {
        int r = rp + (t >> 4);
        int c = (t & 15) * 4;
        int n = n0 + r; if (n >= N) n = N - 1;
        float4 v = reinterpret_cast<const float4*>(u + (size_t)n * 64)[t & 15];
        xs[c + 0][r] = fmaxf(v.x, 0.f); xs[c + 1][r] = fmaxf(v.y, 0.f);
        xs[c + 2][r] = fmaxf(v.z, 0.f); xs[c + 3][r] = fmaxf(v.w, 0.f);
    }
    __syncthreads();

    float4 acc0 = {0,0,0,0}, acc1 = {0,0,0,0}, acc2 = {0,0,0,0}, acc3 = {0,0,0,0};
#pragma unroll 8
    for (int k = 0; k < 64; ++k) {
        float4 xv = *reinterpret_cast<const float4*>(&xs[k][tr * 4]);
        float4 wv = *reinterpret_cast<const float4*>(&wls[k][tc * 4]);
        acc0.x = fmaf(xv.x, wv.x, acc0.x); acc0.y = fmaf(xv.x, wv.y, acc0.y);
        acc0.z = fmaf(xv.x, wv.z, acc0.z); acc0.w = fmaf(xv.x, wv.w, acc0.w);
        acc1.x = fmaf(xv.y, wv.x, acc1.x); acc1.y = fmaf(xv.y, wv.y, acc1.y);
        acc1.z = fmaf(xv.y, wv.z, acc1.z); acc1.w = fmaf(xv.y, wv.w, acc1.w);
        acc2.x = fmaf(xv.z, wv.x, acc2.x); acc2.y = fmaf(xv.z, wv.y, acc2.y);
        acc2.z = fmaf(xv.z, wv.z, acc2.z); acc2.w = fmaf(xv.z, wv.w, acc2.w);
        acc3.x = fmaf(xv.w, wv.x, acc3.x); acc3.y = fmaf(xv.w, wv.y, acc3.y);
        acc3.z = fmaf(xv.w, wv.z, acc3.z); acc3.w = fmaf(xv.w, wv.w, acc3.w);
    }
    int n;
    n = n0 + tr * 4 + 0;
    if (n < N) reinterpret_cast<float4*>(out + (size_t)n * 64)[tc] = acc0;
    n = n0 + tr * 4 + 1;
    if (n < N) reinterpret_cast<float4*>(out + (size_t)n * 64)[tc] = acc1;
    n = n0 + tr * 4 + 2;
    if (n < N) reinterpret_cast<float4*>(out + (size_t)n * 64)[tc] = acc2;
    n = n0 + tr * 4 + 3;
    if (n < N) reinterpret_cast<float4*>(out + (size_t)n * 64)[tc] = acc3;
}

extern "C" void kernel_launch(void* const* d_in, const int* in_sizes, int n_in,
                              void* d_out, int out_size, void* d_ws, size_t ws_size,
                              hipStream_t stream) {
    const float* x  = (const float*)d_in[0];
    const int*   ei = (const int*)d_in[1];
    const float* ew = (const float*)d_in[2];
    const float* We = (const float*)d_in[3];
    const float* Wb = (const float*)d_in[4];
    const float* Wd = (const float*)d_in[5];
    float* out = (float*)d_out;

    const int N = in_sizes[0] / FIN;
    const int E = in_sizes[2];

    char* ws = (char*)d_ws;
    size_t off = 0;
    auto alloc = [&](size_t bytes) -> void* {
        void* p = ws + off;
        off = (off + bytes + 255) & ~(size_t)255;
        return p;
    };
    const size_t nodeb = (size_t)N * H * sizeof(float);
    float* b    = (float*)alloc(nodeb);
    float* ua   = (float*)alloc(nodeb);
    float* ub   = (float*)alloc(nodeb);
    float* uha  = (float*)alloc(nodeb);
    float* uhb  = (float*)alloc(nodeb);
    float* Wc   = (float*)alloc((size_t)FIN * H * sizeof(float));
    int*   rsrt = (int*)alloc((size_t)(N + 1) * sizeof(int));
    int*   cnt  = (int*)alloc((size_t)N * sizeof(int));
    int*   part = (int*)alloc(256 * sizeof(int));
    unsigned long long* epk = (unsigned long long*)alloc((size_t)E * sizeof(unsigned long long));

    const int nb = (N + 1023) / 1024;

    // CSR build
    hipMemsetAsync(cnt, 0, (size_t)N * sizeof(int), stream);
    hist_kernel<<<(E + 255) / 256, 256, 0, stream>>>(ei, cnt, E);
    scan1_kernel<<<nb, 1024, 0, stream>>>(cnt, rsrt, part, N);
    scan2_kernel<<<1, 64, 0, stream>>>(part, nb);
    scan3_kernel<<<nb, 1024, 0, stream>>>(rsrt, part, N);
    copycur_kernel<<<(N + 255) / 256, 256, 0, stream>>>(rsrt, cnt, N);
    scatter_kernel<<<(E + 255) / 256, 256, 0, stream>>>(ei, ew, cnt, epk, E);

    // encoder path: only b is materialized
    wc_kernel<<<FIN * H / 256, 256, 0, stream>>>(We, Wb, Wc);
    benc_kernel<<<(N + 63) / 64, 256, 0, stream>>>(x, Wc, b, N);

    const int sgrid = (N + 3) / 4;
    // first step: u0 = 0, uh0 = -b handled by gathering b directly
    step_kernel<<<sgrid, 256, 0, stream>>>((const float4*)b, (const float4*)b, (const float4*)b,
                                           rsrt, epk, (float4*)ua, (float4*)uha, N, 1);
    float *ucur = ua, *unext = ub, *uhcur = uha, *uhnext = uhb;
    for (int it = 1; it < NIT; ++it) {
        step_kernel<<<sgrid, 256, 0, stream>>>((const float4*)ucur, (const float4*)uhcur,
                                               (const float4*)b, rsrt, epk,
                                               (float4*)unext, (float4*)uhnext, N, 0);
        float* t;
        t = ucur;  ucur  = unext;  unext  = t;
        t = uhcur; uhcur = uhnext; uhnext = t;
    }

    dec_kernel<<<(N + 63) / 64, 256, 0, stream>>>(ucur, Wd, out, N);
}

// Round 3
// 683.214 us; speedup vs baseline: 1.9666x; 1.2394x over previous
//
#include <hip/hip_runtime.h>
#include <hip/hip_fp16.h>

constexpr int H    = 64;     // hidden/out features
constexpr int FIN  = 256;    // input features
constexpr int NIT  = 20;     // fixed-point iterations
// ALPHA = 0.1 folded into benc kernel

__device__ __forceinline__ unsigned f2h2(float a, float b) {
    union { unsigned u; __half2 h; } c;
    c.h = __floats2half2_rn(a, b);
    return c.u;
}

__device__ __forceinline__ void fma8(const uint4& v, float w, float* acc) {
    union { unsigned u; __half2 h; } c0, c1, c2, c3;
    c0.u = v.x; c1.u = v.y; c2.u = v.z; c3.u = v.w;
    float2 f0 = __half22float2(c0.h), f1 = __half22float2(c1.h);
    float2 f2 = __half22float2(c2.h), f3 = __half22float2(c3.h);
    acc[0] = fmaf(w, f0.x, acc[0]); acc[1] = fmaf(w, f0.y, acc[1]);
    acc[2] = fmaf(w, f1.x, acc[2]); acc[3] = fmaf(w, f1.y, acc[3]);
    acc[4] = fmaf(w, f2.x, acc[4]); acc[5] = fmaf(w, f2.y, acc[5]);
    acc[6] = fmaf(w, f3.x, acc[6]); acc[7] = fmaf(w, f3.y, acc[7]);
}

__device__ __forceinline__ void unpack8(const uint4& v, float* f) {
    union { unsigned u; __half2 h; } c0, c1, c2, c3;
    c0.u = v.x; c1.u = v.y; c2.u = v.z; c3.u = v.w;
    float2 f0 = __half22float2(c0.h), f1 = __half22float2(c1.h);
    float2 f2 = __half22float2(c2.h), f3 = __half22float2(c3.h);
    f[0] = f0.x; f[1] = f0.y; f[2] = f1.x; f[3] = f1.y;
    f[4] = f2.x; f[5] = f2.y; f[6] = f3.x; f[7] = f3.y;
}

// ---------------- Wc = W_enc @ W_bias  [FIN x H] ----------------
__global__ __launch_bounds__(256) void wc_kernel(const float* __restrict__ We,
                                                 const float* __restrict__ Wb,
                                                 float* __restrict__ Wc) {
    __shared__ float wb[H * H];
    for (int i = threadIdx.x; i < H * H / 4; i += 256)
        reinterpret_cast<float4*>(wb)[i] = reinterpret_cast<const float4*>(Wb)[i];
    __syncthreads();
    int idx = blockIdx.x * 256 + threadIdx.x;    // 0 .. FIN*H-1
    int i = idx >> 6, j = idx & 63;
    float acc = 0.f;
#pragma unroll 8
    for (int k = 0; k < H; ++k) acc += We[i * H + k] * wb[k * H + j];
    Wc[i * H + j] = acc;
}

// ------------- b_h = fp16( 0.1 * x @ Wc )  (register-tiled 4x4) -------------
__global__ __launch_bounds__(256) void benc_kernel(const float* __restrict__ x,
                                                   const float* __restrict__ Wc,
                                                   unsigned short* __restrict__ bh, int N) {
    __shared__ float xs[64][68];    // transposed x chunk: xs[k][r]
    __shared__ float wls[64][64];   // Wc chunk: wls[k][j]
    const int t  = threadIdx.x;
    const int tr = t >> 4;          // 0..15 row-group
    const int tc = t & 15;          // 0..15 col-group
    const int n0 = blockIdx.x * 64;

    float4 acc0 = {0,0,0,0}, acc1 = {0,0,0,0}, acc2 = {0,0,0,0}, acc3 = {0,0,0,0};

    for (int kc = 0; kc < FIN; kc += 64) {
        __syncthreads();
        for (int i = t; i < 64 * 64 / 4; i += 256)
            reinterpret_cast<float4*>(&wls[0][0])[i] =
                reinterpret_cast<const float4*>(Wc + (size_t)kc * 64)[i];
        for (int rp = 0; rp < 64; rp += 16) {
            int r = rp + (t >> 4);
            int c = (t & 15) * 4;
            int n = n0 + r; if (n >= N) n = N - 1;
            float4 v = reinterpret_cast<const float4*>(x + (size_t)n * FIN + kc)[t & 15];
            xs[c + 0][r] = v.x; xs[c + 1][r] = v.y; xs[c + 2][r] = v.z; xs[c + 3][r] = v.w;
        }
        __syncthreads();
#pragma unroll 8
        for (int k = 0; k < 64; ++k) {
            float4 xv = *reinterpret_cast<const float4*>(&xs[k][tr * 4]);
            float4 wv = *reinterpret_cast<const float4*>(&wls[k][tc * 4]);
            acc0.x = fmaf(xv.x, wv.x, acc0.x); acc0.y = fmaf(xv.x, wv.y, acc0.y);
            acc0.z = fmaf(xv.x, wv.z, acc0.z); acc0.w = fmaf(xv.x, wv.w, acc0.w);
            acc1.x = fmaf(xv.y, wv.x, acc1.x); acc1.y = fmaf(xv.y, wv.y, acc1.y);
            acc1.z = fmaf(xv.y, wv.z, acc1.z); acc1.w = fmaf(xv.y, wv.w, acc1.w);
            acc2.x = fmaf(xv.z, wv.x, acc2.x); acc2.y = fmaf(xv.z, wv.y, acc2.y);
            acc2.z = fmaf(xv.z, wv.z, acc2.z); acc2.w = fmaf(xv.z, wv.w, acc2.w);
            acc3.x = fmaf(xv.w, wv.x, acc3.x); acc3.y = fmaf(xv.w, wv.y, acc3.y);
            acc3.z = fmaf(xv.w, wv.z, acc3.z); acc3.w = fmaf(xv.w, wv.w, acc3.w);
        }
    }
    uint2* bh2 = reinterpret_cast<uint2*>(bh);
    int n;
    n = n0 + tr * 4 + 0;
    if (n < N) bh2[(size_t)n * 16 + tc] =
        make_uint2(f2h2(0.1f*acc0.x, 0.1f*acc0.y), f2h2(0.1f*acc0.z, 0.1f*acc0.w));
    n = n0 + tr * 4 + 1;
    if (n < N) bh2[(size_t)n * 16 + tc] =
        make_uint2(f2h2(0.1f*acc1.x, 0.1f*acc1.y), f2h2(0.1f*acc1.z, 0.1f*acc1.w));
    n = n0 + tr * 4 + 2;
    if (n < N) bh2[(size_t)n * 16 + tc] =
        make_uint2(f2h2(0.1f*acc2.x, 0.1f*acc2.y), f2h2(0.1f*acc2.z, 0.1f*acc2.w));
    n = n0 + tr * 4 + 3;
    if (n < N) bh2[(size_t)n * 16 + tc] =
        make_uint2(f2h2(0.1f*acc3.x, 0.1f*acc3.y), f2h2(0.1f*acc3.z, 0.1f*acc3.w));
}

// ---------------- CSR build ----------------
__global__ __launch_bounds__(256) void hist_kernel(const int* __restrict__ ei, int* __restrict__ cnt, int E) {
    int e = blockIdx.x * 256 + threadIdx.x;
    if (e < E) atomicAdd(&cnt[ei[E + e]], 1);
}

__global__ __launch_bounds__(1024) void scan1_kernel(const int* __restrict__ cnt,
                                                     int* __restrict__ excl,
                                                     int* __restrict__ partials, int n) {
    __shared__ int sd[1024];
    int i = blockIdx.x * 1024 + threadIdx.x;
    sd[threadIdx.x] = (i < n) ? cnt[i] : 0;
    __syncthreads();
    for (int off = 1; off < 1024; off <<= 1) {
        int t = (threadIdx.x >= (unsigned)off) ? sd[threadIdx.x - off] : 0;
        __syncthreads();
        sd[threadIdx.x] += t;
        __syncthreads();
    }
    if (i < n) excl[i + 1] = sd[threadIdx.x];
    if (threadIdx.x == 1023) partials[blockIdx.x] = sd[1023];
}

__global__ void scan2_kernel(int* __restrict__ partials, int nb) {
    int lane = threadIdx.x;               // single wave of 64, nb <= 64
    int v = (lane < nb) ? partials[lane] : 0;
    for (int off = 1; off < 64; off <<= 1) {
        int t = __shfl_up(v, off);
        if (lane >= off) v += t;
    }
    int ex = __shfl_up(v, 1);
    if (lane == 0) ex = 0;
    if (lane < nb) partials[lane] = ex;
}

// also writes the scatter cursor array (fused copycur)
__global__ __launch_bounds__(1024) void scan3_kernel(int* __restrict__ excl,
                                                     int* __restrict__ cur,
                                                     const int* __restrict__ partials, int n) {
    int i = blockIdx.x * 1024 + threadIdx.x;
    if (i < n) {
        int v = excl[i + 1] + partials[blockIdx.x];
        excl[i + 1] = v;
        if (i + 1 < n) cur[i + 1] = v;
    }
    if (i == 0) { excl[0] = 0; cur[0] = 0; }
}

// pack (fp16 w | u16 src) into one 4B word at CSR position
__global__ __launch_bounds__(256) void scatter_kernel(const int* __restrict__ ei,
                                                      const float* __restrict__ ew,
                                                      int* __restrict__ cur,
                                                      unsigned* __restrict__ epk, int E) {
    int e = blockIdx.x * 256 + threadIdx.x;
    if (e < E) {
        int d = ei[E + e];
        int pos = atomicAdd(&cur[d], 1);
        union { __half h; unsigned short us; } cv;
        cv.h = __float2half_rn(ew[e]);
        epk[pos] = ((unsigned)cv.us << 16) | (unsigned)(ei[e] & 0xffff);
    }
}

// ---------------- one Peaceman-Rachford step (fused) ----------------
// normal:  un = 2*V(uh) - 2*relu(u) + u ;  uh_next = fp16(2*relu(un) - un - b)
// first :  gather source = b_h, u == 0  =>  un = -2*V(b)
// lane layout: sub = lane>>3 (edge subgroup, 8 edges in flight),
//              fo  = lane&7  (feature octet: 8 fp16 = 16B per lane)
__global__ __launch_bounds__(256) void step_kernel(const float4* __restrict__ u,
                                                   const uint4* __restrict__ gh,   // fp16 rows [N*8]
                                                   const uint4* __restrict__ bh,   // fp16 rows [N*8]
                                                   const int* __restrict__ row_start,
                                                   const unsigned* __restrict__ epk,
                                                   float4* __restrict__ u_next,
                                                   uint4* __restrict__ uh_next,
                                                   int N, int is_first) {
    int node = blockIdx.x * 4 + (threadIdx.x >> 6);
    if (node >= N) return;
    int lane = threadIdx.x & 63;
    int sub  = lane >> 3;
    int fo   = lane & 7;
    int e0 = row_start[node];
    int e1 = row_start[node + 1];

    float a0[8] = {0,0,0,0,0,0,0,0};
    float a1[8] = {0,0,0,0,0,0,0,0};
    int e = e0 + sub;
    for (; e + 8 < e1; e += 16) {
        unsigned p0 = epk[e];
        unsigned p1 = epk[e + 8];
        int s0 = (int)(p0 & 0xffffu);
        int s1 = (int)(p1 & 0xffffu);
        union { unsigned short us; __half h; } w0c, w1c;
        w0c.us = (unsigned short)(p0 >> 16);
        w1c.us = (unsigned short)(p1 >> 16);
        float w0 = __half2float(w0c.h);
        float w1 = __half2float(w1c.h);
        uint4 v0 = gh[(size_t)s0 * 8 + fo];
        uint4 v1 = gh[(size_t)s1 * 8 + fo];
        fma8(v0, w0, a0);
        fma8(v1, w1, a1);
    }
    if (e < e1) {
        unsigned p0 = epk[e];
        int s0 = (int)(p0 & 0xffffu);
        union { unsigned short us; __half h; } w0c;
        w0c.us = (unsigned short)(p0 >> 16);
        float w0 = __half2float(w0c.h);
        uint4 v0 = gh[(size_t)s0 * 8 + fo];
        fma8(v0, w0, a0);
    }
    float s[8];
#pragma unroll
    for (int i = 0; i < 8; ++i) {
        float v = a0[i] + a1[i];
        v += __shfl_xor(v, 8);
        v += __shfl_xor(v, 16);
        v += __shfl_xor(v, 32);
        s[i] = v;
    }

    if (lane < 8) {   // sub == 0; fo == lane
        size_t r8 = (size_t)node * 8 + fo;
        float bf[8];
        unpack8(bh[r8], bf);
        float un[8];
        if (is_first) {
#pragma unroll
            for (int i = 0; i < 8; ++i) un[i] = -2.f * s[i];
        } else {
            float4 ua = u[(size_t)node * 16 + fo * 2];
            float4 ub = u[(size_t)node * 16 + fo * 2 + 1];
            float uv[8] = {ua.x, ua.y, ua.z, ua.w, ub.x, ub.y, ub.z, ub.w};
#pragma unroll
            for (int i = 0; i < 8; ++i)
                un[i] = 2.f * s[i] - 2.f * fmaxf(uv[i], 0.f) + uv[i];
        }
        float uhn[8];
#pragma unroll
        for (int i = 0; i < 8; ++i)
            uhn[i] = 2.f * fmaxf(un[i], 0.f) - un[i] - bf[i];
        float4 o0 = {un[0], un[1], un[2], un[3]};
        float4 o1 = {un[4], un[5], un[6], un[7]};
        u_next[(size_t)node * 16 + fo * 2]     = o0;
        u_next[(size_t)node * 16 + fo * 2 + 1] = o1;
        uint4 oh;
        oh.x = f2h2(uhn[0], uhn[1]); oh.y = f2h2(uhn[2], uhn[3]);
        oh.z = f2h2(uhn[4], uhn[5]); oh.w = f2h2(uhn[6], uhn[7]);
        uh_next[r8] = oh;
    }
}

// ---------------- out = relu(u) @ W_dec  (register-tiled 4x4) ----------------
__global__ __launch_bounds__(256) void dec_kernel(const float* __restrict__ u,
                                                  const float* __restrict__ Wd,
                                                  float* __restrict__ out, int N) {
    __shared__ float xs[64][68];    // transposed relu(u) chunk
    __shared__ float wls[64][64];
    const int t  = threadIdx.x;
    const int tr = t >> 4;
    const int tc = t & 15;
    const int n0 = blockIdx.x * 64;

    for (int i = t; i < 64 * 64 / 4; i += 256)
        reinterpret_cast<float4*>(&wls[0][0])[i] = reinterpret_cast<const float4*>(Wd)[i];
    for (int rp = 0; rp < 64; rp += 16) {
        int r = rp + (t >> 4);
        int c = (t & 15) * 4;
        int n = n0 + r; if (n >= N) n = N - 1;
        float4 v = reinterpret_cast<const float4*>(u + (size_t)n * 64)[t & 15];
        xs[c + 0][r] = fmaxf(v.x, 0.f); xs[c + 1][r] = fmaxf(v.y, 0.f);
        xs[c + 2][r] = fmaxf(v.z, 0.f); xs[c + 3][r] = fmaxf(v.w, 0.f);
    }
    __syncthreads();

    float4 acc0 = {0,0,0,0}, acc1 = {0,0,0,0}, acc2 = {0,0,0,0}, acc3 = {0,0,0,0};
#pragma unroll 8
    for (int k = 0; k < 64; ++k) {
        float4 xv = *reinterpret_cast<const float4*>(&xs[k][tr * 4]);
        float4 wv = *reinterpret_cast<const float4*>(&wls[k][tc * 4]);
        acc0.x = fmaf(xv.x, wv.x, acc0.x); acc0.y = fmaf(xv.x, wv.y, acc0.y);
        acc0.z = fmaf(xv.x, wv.z, acc0.z); acc0.w = fmaf(xv.x, wv.w, acc0.w);
        acc1.x = fmaf(xv.y, wv.x, acc1.x); acc1.y = fmaf(xv.y, wv.y, acc1.y);
        acc1.z = fmaf(xv.y, wv.z, acc1.z); acc1.w = fmaf(xv.y, wv.w, acc1.w);
        acc2.x = fmaf(xv.z, wv.x, acc2.x); acc2.y = fmaf(xv.z, wv.y, acc2.y);
        acc2.z = fmaf(xv.z, wv.z, acc2.z); acc2.w = fmaf(xv.z, wv.w, acc2.w);
        acc3.x = fmaf(xv.w, wv.x, acc3.x); acc3.y = fmaf(xv.w, wv.y, acc3.y);
        acc3.z = fmaf(xv.w, wv.z, acc3.z); acc3.w = fmaf(xv.w, wv.w, acc3.w);
    }
    int n;
    n = n0 + tr * 4 + 0;
    if (n < N) reinterpret_cast<float4*>(out + (size_t)n * 64)[tc] = acc0;
    n = n0 + tr * 4 + 1;
    if (n < N) reinterpret_cast<float4*>(out + (size_t)n * 64)[tc] = acc1;
    n = n0 + tr * 4 + 2;
    if (n < N) reinterpret_cast<float4*>(out + (size_t)n * 64)[tc] = acc2;
    n = n0 + tr * 4 + 3;
    if (n < N) reinterpret_cast<float4*>(out + (size_t)n * 64)[tc] = acc3;
}

extern "C" void kernel_launch(void* const* d_in, const int* in_sizes, int n_in,
                              void* d_out, int out_size, void* d_ws, size_t ws_size,
                              hipStream_t stream) {
    const float* x  = (const float*)d_in[0];
    const int*   ei = (const int*)d_in[1];
    const float* ew = (const float*)d_in[2];
    const float* We = (const float*)d_in[3];
    const float* Wb = (const float*)d_in[4];
    const float* Wd = (const float*)d_in[5];
    float* out = (float*)d_out;

    const int N = in_sizes[0] / FIN;
    const int E = in_sizes[2];

    char* ws = (char*)d_ws;
    size_t off = 0;
    auto alloc = [&](size_t bytes) -> void* {
        void* p = ws + off;
        off = (off + bytes + 255) & ~(size_t)255;
        return p;
    };
    const size_t nodef32 = (size_t)N * H * sizeof(float);
    const size_t nodef16 = (size_t)N * H * sizeof(unsigned short);
    unsigned short* bh  = (unsigned short*)alloc(nodef16);
    float* ua   = (float*)alloc(nodef32);
    float* ub   = (float*)alloc(nodef32);
    unsigned short* uhha = (unsigned short*)alloc(nodef16);
    unsigned short* uhhb = (unsigned short*)alloc(nodef16);
    float* Wc   = (float*)alloc((size_t)FIN * H * sizeof(float));
    int*   rsrt = (int*)alloc((size_t)(N + 1) * sizeof(int));
    int*   cnt  = (int*)alloc((size_t)N * sizeof(int));
    int*   part = (int*)alloc(256 * sizeof(int));
    unsigned* epk = (unsigned*)alloc((size_t)E * sizeof(unsigned));

    const int nb = (N + 1023) / 1024;

    // CSR build
    hipMemsetAsync(cnt, 0, (size_t)N * sizeof(int), stream);
    hist_kernel<<<(E + 255) / 256, 256, 0, stream>>>(ei, cnt, E);
    scan1_kernel<<<nb, 1024, 0, stream>>>(cnt, rsrt, part, N);
    scan2_kernel<<<1, 64, 0, stream>>>(part, nb);
    scan3_kernel<<<nb, 1024, 0, stream>>>(rsrt, cnt, part, N);
    scatter_kernel<<<(E + 255) / 256, 256, 0, stream>>>(ei, ew, cnt, epk, E);

    // encoder path: only b (fp16) is materialized
    wc_kernel<<<FIN * H / 256, 256, 0, stream>>>(We, Wb, Wc);
    benc_kernel<<<(N + 63) / 64, 256, 0, stream>>>(x, Wc, bh, N);

    const int sgrid = (N + 3) / 4;
    // first step: u0 = 0, uh0 = -b handled by gathering b_h with sign flip
    step_kernel<<<sgrid, 256, 0, stream>>>((const float4*)ua, (const uint4*)bh, (const uint4*)bh,
                                           rsrt, epk, (float4*)ua, (uint4*)uhha, N, 1);
    float *ucur = ua, *unext = ub;
    unsigned short *uhcur = uhha, *uhnext = uhhb;
    for (int it = 1; it < NIT; ++it) {
        step_kernel<<<sgrid, 256, 0, stream>>>((const float4*)ucur, (const uint4*)uhcur,
                                               (const uint4*)bh, rsrt, epk,
                                               (float4*)unext, (uint4*)uhnext, N, 0);
        float* t;
        t = ucur; ucur = unext; unext = t;
        unsigned short* th;
        th = uhcur; uhcur = uhnext; uhnext = th;
    }

    dec_kernel<<<(N + 63) / 64, 256, 0, stream>>>(ucur, Wd, out, N);
}

// Round 4
// 651.132 us; speedup vs baseline: 2.0635x; 1.0493x over previous
//
#include <hip/hip_runtime.h>
#include <hip/hip_fp16.h>

constexpr int H    = 64;     // hidden/out features
constexpr int FIN  = 256;    // input features
constexpr int NIT  = 20;     // fixed-point iterations
// ALPHA = 0.1 folded into benc kernel

__device__ __forceinline__ unsigned f2h2(float a, float b) {
    union { unsigned u; __half2 h; } c;
    c.h = __floats2half2_rn(a, b);
    return c.u;
}

__device__ __forceinline__ void fma8(const uint4& v, float w, float* acc) {
    union { unsigned u; __half2 h; } c0, c1, c2, c3;
    c0.u = v.x; c1.u = v.y; c2.u = v.z; c3.u = v.w;
    float2 f0 = __half22float2(c0.h), f1 = __half22float2(c1.h);
    float2 f2 = __half22float2(c2.h), f3 = __half22float2(c3.h);
    acc[0] = fmaf(w, f0.x, acc[0]); acc[1] = fmaf(w, f0.y, acc[1]);
    acc[2] = fmaf(w, f1.x, acc[2]); acc[3] = fmaf(w, f1.y, acc[3]);
    acc[4] = fmaf(w, f2.x, acc[4]); acc[5] = fmaf(w, f2.y, acc[5]);
    acc[6] = fmaf(w, f3.x, acc[6]); acc[7] = fmaf(w, f3.y, acc[7]);
}

__device__ __forceinline__ void unpack8(const uint4& v, float* f) {
    union { unsigned u; __half2 h; } c0, c1, c2, c3;
    c0.u = v.x; c1.u = v.y; c2.u = v.z; c3.u = v.w;
    float2 f0 = __half22float2(c0.h), f1 = __half22float2(c1.h);
    float2 f2 = __half22float2(c2.h), f3 = __half22float2(c3.h);
    f[0] = f0.x; f[1] = f0.y; f[2] = f1.x; f[3] = f1.y;
    f[4] = f2.x; f[5] = f2.y; f[6] = f3.x; f[7] = f3.y;
}

// ---------------- Wc = W_enc @ W_bias  [FIN x H] ----------------
__global__ __launch_bounds__(256) void wc_kernel(const float* __restrict__ We,
                                                 const float* __restrict__ Wb,
                                                 float* __restrict__ Wc) {
    __shared__ float wb[H * H];
    for (int i = threadIdx.x; i < H * H / 4; i += 256)
        reinterpret_cast<float4*>(wb)[i] = reinterpret_cast<const float4*>(Wb)[i];
    __syncthreads();
    int idx = blockIdx.x * 256 + threadIdx.x;    // 0 .. FIN*H-1
    int i = idx >> 6, j = idx & 63;
    float acc = 0.f;
#pragma unroll 8
    for (int k = 0; k < H; ++k) acc += We[i * H + k] * wb[k * H + j];
    Wc[i * H + j] = acc;
}

// ------------- b_h = fp16( 0.1 * x @ Wc )  (register-tiled 4x4) -------------
__global__ __launch_bounds__(256) void benc_kernel(const float* __restrict__ x,
                                                   const float* __restrict__ Wc,
                                                   unsigned short* __restrict__ bh, int N) {
    __shared__ float xs[64][68];    // transposed x chunk: xs[k][r]
    __shared__ float wls[64][64];   // Wc chunk: wls[k][j]
    const int t  = threadIdx.x;
    const int tr = t >> 4;          // 0..15 row-group
    const int tc = t & 15;          // 0..15 col-group
    const int n0 = blockIdx.x * 64;

    float4 acc0 = {0,0,0,0}, acc1 = {0,0,0,0}, acc2 = {0,0,0,0}, acc3 = {0,0,0,0};

    for (int kc = 0; kc < FIN; kc += 64) {
        __syncthreads();
        for (int i = t; i < 64 * 64 / 4; i += 256)
            reinterpret_cast<float4*>(&wls[0][0])[i] =
                reinterpret_cast<const float4*>(Wc + (size_t)kc * 64)[i];
        for (int rp = 0; rp < 64; rp += 16) {
            int r = rp + (t >> 4);
            int c = (t & 15) * 4;
            int n = n0 + r; if (n >= N) n = N - 1;
            float4 v = reinterpret_cast<const float4*>(x + (size_t)n * FIN + kc)[t & 15];
            xs[c + 0][r] = v.x; xs[c + 1][r] = v.y; xs[c + 2][r] = v.z; xs[c + 3][r] = v.w;
        }
        __syncthreads();
#pragma unroll 8
        for (int k = 0; k < 64; ++k) {
            float4 xv = *reinterpret_cast<const float4*>(&xs[k][tr * 4]);
            float4 wv = *reinterpret_cast<const float4*>(&wls[k][tc * 4]);
            acc0.x = fmaf(xv.x, wv.x, acc0.x); acc0.y = fmaf(xv.x, wv.y, acc0.y);
            acc0.z = fmaf(xv.x, wv.z, acc0.z); acc0.w = fmaf(xv.x, wv.w, acc0.w);
            acc1.x = fmaf(xv.y, wv.x, acc1.x); acc1.y = fmaf(xv.y, wv.y, acc1.y);
            acc1.z = fmaf(xv.y, wv.z, acc1.z); acc1.w = fmaf(xv.y, wv.w, acc1.w);
            acc2.x = fmaf(xv.z, wv.x, acc2.x); acc2.y = fmaf(xv.z, wv.y, acc2.y);
            acc2.z = fmaf(xv.z, wv.z, acc2.z); acc2.w = fmaf(xv.z, wv.w, acc2.w);
            acc3.x = fmaf(xv.w, wv.x, acc3.x); acc3.y = fmaf(xv.w, wv.y, acc3.y);
            acc3.z = fmaf(xv.w, wv.z, acc3.z); acc3.w = fmaf(xv.w, wv.w, acc3.w);
        }
    }
    uint2* bh2 = reinterpret_cast<uint2*>(bh);
    int n;
    n = n0 + tr * 4 + 0;
    if (n < N) bh2[(size_t)n * 16 + tc] =
        make_uint2(f2h2(0.1f*acc0.x, 0.1f*acc0.y), f2h2(0.1f*acc0.z, 0.1f*acc0.w));
    n = n0 + tr * 4 + 1;
    if (n < N) bh2[(size_t)n * 16 + tc] =
        make_uint2(f2h2(0.1f*acc1.x, 0.1f*acc1.y), f2h2(0.1f*acc1.z, 0.1f*acc1.w));
    n = n0 + tr * 4 + 2;
    if (n < N) bh2[(size_t)n * 16 + tc] =
        make_uint2(f2h2(0.1f*acc2.x, 0.1f*acc2.y), f2h2(0.1f*acc2.z, 0.1f*acc2.w));
    n = n0 + tr * 4 + 3;
    if (n < N) bh2[(size_t)n * 16 + tc] =
        make_uint2(f2h2(0.1f*acc3.x, 0.1f*acc3.y), f2h2(0.1f*acc3.z, 0.1f*acc3.w));
}

// ---------------- CSR build ----------------
__global__ __launch_bounds__(256) void hist_kernel(const int* __restrict__ ei, int* __restrict__ cnt, int E) {
    int e = blockIdx.x * 256 + threadIdx.x;
    if (e < E) atomicAdd(&cnt[ei[E + e]], 1);
}

__global__ __launch_bounds__(1024) void scan1_kernel(const int* __restrict__ cnt,
                                                     int* __restrict__ excl,
                                                     int* __restrict__ partials, int n) {
    __shared__ int sd[1024];
    int i = blockIdx.x * 1024 + threadIdx.x;
    sd[threadIdx.x] = (i < n) ? cnt[i] : 0;
    __syncthreads();
    for (int off = 1; off < 1024; off <<= 1) {
        int t = (threadIdx.x >= (unsigned)off) ? sd[threadIdx.x - off] : 0;
        __syncthreads();
        sd[threadIdx.x] += t;
        __syncthreads();
    }
    if (i < n) excl[i + 1] = sd[threadIdx.x];
    if (threadIdx.x == 1023) partials[blockIdx.x] = sd[1023];
}

__global__ void scan2_kernel(int* __restrict__ partials, int nb) {
    int lane = threadIdx.x;               // single wave of 64, nb <= 64
    int v = (lane < nb) ? partials[lane] : 0;
    for (int off = 1; off < 64; off <<= 1) {
        int t = __shfl_up(v, off);
        if (lane >= off) v += t;
    }
    int ex = __shfl_up(v, 1);
    if (lane == 0) ex = 0;
    if (lane < nb) partials[lane] = ex;
}

// also writes the scatter cursor array (fused copycur)
__global__ __launch_bounds__(1024) void scan3_kernel(int* __restrict__ excl,
                                                     int* __restrict__ cur,
                                                     const int* __restrict__ partials, int n) {
    int i = blockIdx.x * 1024 + threadIdx.x;
    if (i < n) {
        int v = excl[i + 1] + partials[blockIdx.x];
        excl[i + 1] = v;
        if (i + 1 < n) cur[i + 1] = v;
    }
    if (i == 0) { excl[0] = 0; cur[0] = 0; }
}

// pack (fp16 w | u16 src) into one 4B word at CSR position
__global__ __launch_bounds__(256) void scatter_kernel(const int* __restrict__ ei,
                                                      const float* __restrict__ ew,
                                                      int* __restrict__ cur,
                                                      unsigned* __restrict__ epk, int E) {
    int e = blockIdx.x * 256 + threadIdx.x;
    if (e < E) {
        int d = ei[E + e];
        int pos = atomicAdd(&cur[d], 1);
        union { __half h; unsigned short us; } cv;
        cv.h = __float2half_rn(ew[e]);
        epk[pos] = ((unsigned)cv.us << 16) | (unsigned)(ei[e] & 0xffff);
    }
}

// ---------------- one Peaceman-Rachford step (uh-only state) ----------------
// identity: 2*relu(u) - u = |u|  =>  uh = |u| - b ;  un = 2*V(uh) - uh - b
// normal:  s = V(uh_n);  un = 2s - uh_n - b;  out = fp16(|un| - b)
// first :  gather source = bh (uh_0 = -b):  s' = V(b);  un = -2s'
// last  :  out = fp16(relu(un))   (decoder input)
// lane layout: sub = lane>>3 (edge subgroup, 8 edges in flight),
//              fo  = lane&7  (feature octet: 8 fp16 = 16B per lane)
__global__ __launch_bounds__(256) void step_kernel(const uint4* __restrict__ gh,  // gather rows [N*8]
                                                   const uint4* __restrict__ uhr, // own uh row [N*8]
                                                   const uint4* __restrict__ bh,  // b rows [N*8]
                                                   const int* __restrict__ row_start,
                                                   const unsigned* __restrict__ epk,
                                                   uint4* __restrict__ outh,      // uh_next or relu(u)
                                                   int N, int is_first, int is_last) {
    int node = blockIdx.x * 4 + (threadIdx.x >> 6);
    if (node >= N) return;
    int lane = threadIdx.x & 63;
    int sub  = lane >> 3;
    int fo   = lane & 7;
    int e0 = row_start[node];
    int e1 = row_start[node + 1];

    float a0[8] = {0,0,0,0,0,0,0,0};
    float a1[8] = {0,0,0,0,0,0,0,0};
    int e = e0 + sub;
    for (; e + 8 < e1; e += 16) {
        unsigned p0 = epk[e];
        unsigned p1 = epk[e + 8];
        int s0 = (int)(p0 & 0xffffu);
        int s1 = (int)(p1 & 0xffffu);
        union { unsigned short us; __half h; } w0c, w1c;
        w0c.us = (unsigned short)(p0 >> 16);
        w1c.us = (unsigned short)(p1 >> 16);
        float w0 = __half2float(w0c.h);
        float w1 = __half2float(w1c.h);
        uint4 v0 = gh[(size_t)s0 * 8 + fo];
        uint4 v1 = gh[(size_t)s1 * 8 + fo];
        fma8(v0, w0, a0);
        fma8(v1, w1, a1);
    }
    if (e < e1) {
        unsigned p0 = epk[e];
        int s0 = (int)(p0 & 0xffffu);
        union { unsigned short us; __half h; } w0c;
        w0c.us = (unsigned short)(p0 >> 16);
        float w0 = __half2float(w0c.h);
        uint4 v0 = gh[(size_t)s0 * 8 + fo];
        fma8(v0, w0, a0);
    }
    float s[8];
#pragma unroll
    for (int i = 0; i < 8; ++i) {
        float v = a0[i] + a1[i];
        v += __shfl_xor(v, 8);
        v += __shfl_xor(v, 16);
        v += __shfl_xor(v, 32);
        s[i] = v;
    }

    if (lane < 8) {   // sub == 0; fo == lane
        size_t r8 = (size_t)node * 8 + fo;
        float bf[8];
        unpack8(bh[r8], bf);
        float un[8];
        if (is_first) {
#pragma unroll
            for (int i = 0; i < 8; ++i) un[i] = -2.f * s[i];
        } else {
            float uhv[8];
            unpack8(uhr[r8], uhv);
#pragma unroll
            for (int i = 0; i < 8; ++i)
                un[i] = 2.f * s[i] - uhv[i] - bf[i];
        }
        float ov[8];
        if (is_last) {
#pragma unroll
            for (int i = 0; i < 8; ++i) ov[i] = fmaxf(un[i], 0.f);
        } else {
#pragma unroll
            for (int i = 0; i < 8; ++i) ov[i] = fabsf(un[i]) - bf[i];
        }
        uint4 oh;
        oh.x = f2h2(ov[0], ov[1]); oh.y = f2h2(ov[2], ov[3]);
        oh.z = f2h2(ov[4], ov[5]); oh.w = f2h2(ov[6], ov[7]);
        outh[r8] = oh;
    }
}

// ------------- out = rh @ W_dec, rh already relu'd fp16 (register-tiled 4x4) -------------
__global__ __launch_bounds__(256) void dec_kernel(const uint4* __restrict__ rh,
                                                  const float* __restrict__ Wd,
                                                  float* __restrict__ out, int N) {
    __shared__ float xs[64][68];    // transposed rh chunk
    __shared__ float wls[64][64];
    const int t  = threadIdx.x;
    const int tr = t >> 4;
    const int tc = t & 15;
    const int n0 = blockIdx.x * 64;

    for (int i = t; i < 64 * 64 / 4; i += 256)
        reinterpret_cast<float4*>(&wls[0][0])[i] = reinterpret_cast<const float4*>(Wd)[i];
    for (int rp = 0; rp < 64; rp += 32) {
        int r = rp + (t >> 3);
        int c = (t & 7) * 8;
        int n = n0 + r; if (n >= N) n = N - 1;
        uint4 v = rh[(size_t)n * 8 + (t & 7)];
        float f[8];
        unpack8(v, f);
#pragma unroll
        for (int i = 0; i < 8; ++i) xs[c + i][r] = f[i];
    }
    __syncthreads();

    float4 acc0 = {0,0,0,0}, acc1 = {0,0,0,0}, acc2 = {0,0,0,0}, acc3 = {0,0,0,0};
#pragma unroll 8
    for (int k = 0; k < 64; ++k) {
        float4 xv = *reinterpret_cast<const float4*>(&xs[k][tr * 4]);
        float4 wv = *reinterpret_cast<const float4*>(&wls[k][tc * 4]);
        acc0.x = fmaf(xv.x, wv.x, acc0.x); acc0.y = fmaf(xv.x, wv.y, acc0.y);
        acc0.z = fmaf(xv.x, wv.z, acc0.z); acc0.w = fmaf(xv.x, wv.w, acc0.w);
        acc1.x = fmaf(xv.y, wv.x, acc1.x); acc1.y = fmaf(xv.y, wv.y, acc1.y);
        acc1.z = fmaf(xv.y, wv.z, acc1.z); acc1.w = fmaf(xv.y, wv.w, acc1.w);
        acc2.x = fmaf(xv.z, wv.x, acc2.x); acc2.y = fmaf(xv.z, wv.y, acc2.y);
        acc2.z = fmaf(xv.z, wv.z, acc2.z); acc2.w = fmaf(xv.z, wv.w, acc2.w);
        acc3.x = fmaf(xv.w, wv.x, acc3.x); acc3.y = fmaf(xv.w, wv.y, acc3.y);
        acc3.z = fmaf(xv.w, wv.z, acc3.z); acc3.w = fmaf(xv.w, wv.w, acc3.w);
    }
    int n;
    n = n0 + tr * 4 + 0;
    if (n < N) reinterpret_cast<float4*>(out + (size_t)n * 64)[tc] = acc0;
    n = n0 + tr * 4 + 1;
    if (n < N) reinterpret_cast<float4*>(out + (size_t)n * 64)[tc] = acc1;
    n = n0 + tr * 4 + 2;
    if (n < N) reinterpret_cast<float4*>(out + (size_t)n * 64)[tc] = acc2;
    n = n0 + tr * 4 + 3;
    if (n < N) reinterpret_cast<float4*>(out + (size_t)n * 64)[tc] = acc3;
}

extern "C" void kernel_launch(void* const* d_in, const int* in_sizes, int n_in,
                              void* d_out, int out_size, void* d_ws, size_t ws_size,
                              hipStream_t stream) {
    const float* x  = (const float*)d_in[0];
    const int*   ei = (const int*)d_in[1];
    const float* ew = (const float*)d_in[2];
    const float* We = (const float*)d_in[3];
    const float* Wb = (const float*)d_in[4];
    const float* Wd = (const float*)d_in[5];
    float* out = (float*)d_out;

    const int N = in_sizes[0] / FIN;
    const int E = in_sizes[2];

    char* ws = (char*)d_ws;
    size_t off = 0;
    auto alloc = [&](size_t bytes) -> void* {
        void* p = ws + off;
        off = (off + bytes + 255) & ~(size_t)255;
        return p;
    };
    const size_t nodef16 = (size_t)N * H * sizeof(unsigned short);
    unsigned short* bh   = (unsigned short*)alloc(nodef16);
    unsigned short* uhha = (unsigned short*)alloc(nodef16);
    unsigned short* uhhb = (unsigned short*)alloc(nodef16);
    float* Wc   = (float*)alloc((size_t)FIN * H * sizeof(float));
    int*   rsrt = (int*)alloc((size_t)(N + 1) * sizeof(int));
    int*   cnt  = (int*)alloc((size_t)N * sizeof(int));
    int*   part = (int*)alloc(256 * sizeof(int));
    unsigned* epk = (unsigned*)alloc((size_t)E * sizeof(unsigned));

    const int nb = (N + 1023) / 1024;

    // CSR build
    hipMemsetAsync(cnt, 0, (size_t)N * sizeof(int), stream);
    hist_kernel<<<(E + 255) / 256, 256, 0, stream>>>(ei, cnt, E);
    scan1_kernel<<<nb, 1024, 0, stream>>>(cnt, rsrt, part, N);
    scan2_kernel<<<1, 64, 0, stream>>>(part, nb);
    scan3_kernel<<<nb, 1024, 0, stream>>>(rsrt, cnt, part, N);
    scatter_kernel<<<(E + 255) / 256, 256, 0, stream>>>(ei, ew, cnt, epk, E);

    // encoder path: only b (fp16) is materialized
    wc_kernel<<<FIN * H / 256, 256, 0, stream>>>(We, Wb, Wc);
    benc_kernel<<<(N + 63) / 64, 256, 0, stream>>>(x, Wc, bh, N);

    const int sgrid = (N + 3) / 4;
    // first step: uh_0 = -b handled by gathering bh with sign flip
    step_kernel<<<sgrid, 256, 0, stream>>>((const uint4*)bh, (const uint4*)bh, (const uint4*)bh,
                                           rsrt, epk, (uint4*)uhha, N, 1, 0);
    unsigned short *uhcur = uhha, *uhnext = uhhb;
    for (int it = 1; it < NIT; ++it) {
        int last = (it == NIT - 1) ? 1 : 0;
        step_kernel<<<sgrid, 256, 0, stream>>>((const uint4*)uhcur, (const uint4*)uhcur,
                                               (const uint4*)bh, rsrt, epk,
                                               (uint4*)uhnext, N, 0, last);
        unsigned short* th;
        th = uhcur; uhcur = uhnext; uhnext = th;
    }

    // uhcur now holds fp16 relu(u_20)
    dec_kernel<<<(N + 63) / 64, 256, 0, stream>>>((const uint4*)uhcur, Wd, out, N);
}

// Round 5
// 532.322 us; speedup vs baseline: 2.5241x; 1.2232x over previous
//
#include <hip/hip_runtime.h>
#include <hip/hip_fp16.h>

constexpr int H    = 64;     // hidden/out features
constexpr int FIN  = 256;    // input features
constexpr int NIT  = 20;     // fixed-point iterations
// ALPHA = 0.1 folded into benc kernel

__device__ __forceinline__ unsigned f2h2(float a, float b) {
    union { unsigned u; __half2 h; } c;
    c.h = __floats2half2_rn(a, b);
    return c.u;
}

__device__ __forceinline__ unsigned short f2hbits(float a) {
    union { __half h; unsigned short us; } c;
    c.h = __float2half_rn(a);
    return c.us;
}

__device__ __forceinline__ void fma8(const uint4& v, float w, float* acc) {
    union { unsigned u; __half2 h; } c0, c1, c2, c3;
    c0.u = v.x; c1.u = v.y; c2.u = v.z; c3.u = v.w;
    float2 f0 = __half22float2(c0.h), f1 = __half22float2(c1.h);
    float2 f2 = __half22float2(c2.h), f3 = __half22float2(c3.h);
    acc[0] = fmaf(w, f0.x, acc[0]); acc[1] = fmaf(w, f0.y, acc[1]);
    acc[2] = fmaf(w, f1.x, acc[2]); acc[3] = fmaf(w, f1.y, acc[3]);
    acc[4] = fmaf(w, f2.x, acc[4]); acc[5] = fmaf(w, f2.y, acc[5]);
    acc[6] = fmaf(w, f3.x, acc[6]); acc[7] = fmaf(w, f3.y, acc[7]);
}

__device__ __forceinline__ void unpack8(const uint4& v, float* f) {
    union { unsigned u; __half2 h; } c0, c1, c2, c3;
    c0.u = v.x; c1.u = v.y; c2.u = v.z; c3.u = v.w;
    float2 f0 = __half22float2(c0.h), f1 = __half22float2(c1.h);
    float2 f2 = __half22float2(c2.h), f3 = __half22float2(c3.h);
    f[0] = f0.x; f[1] = f0.y; f[2] = f1.x; f[3] = f1.y;
    f[4] = f2.x; f[5] = f2.y; f[6] = f3.x; f[7] = f3.y;
}

// ---------------- Wc = W_enc @ W_bias  [FIN x H] ----------------
__global__ __launch_bounds__(256) void wc_kernel(const float* __restrict__ We,
                                                 const float* __restrict__ Wb,
                                                 float* __restrict__ Wc) {
    __shared__ float wb[H * H];
    for (int i = threadIdx.x; i < H * H / 4; i += 256)
        reinterpret_cast<float4*>(wb)[i] = reinterpret_cast<const float4*>(Wb)[i];
    __syncthreads();
    int idx = blockIdx.x * 256 + threadIdx.x;    // 0 .. FIN*H-1
    int i = idx >> 6, j = idx & 63;
    float acc = 0.f;
#pragma unroll 8
    for (int k = 0; k < H; ++k) acc += We[i * H + k] * wb[k * H + j];
    Wc[i * H + j] = acc;
}

// ------------- b_h = fp16( 0.1 * x @ Wc )  (register-tiled 4x4) -------------
__global__ __launch_bounds__(256) void benc_kernel(const float* __restrict__ x,
                                                   const float* __restrict__ Wc,
                                                   unsigned short* __restrict__ bh, int N) {
    __shared__ float xs[64][68];    // transposed x chunk: xs[k][r]
    __shared__ float wls[64][64];   // Wc chunk: wls[k][j]
    const int t  = threadIdx.x;
    const int tr = t >> 4;          // 0..15 row-group
    const int tc = t & 15;          // 0..15 col-group
    const int n0 = blockIdx.x * 64;

    float4 acc0 = {0,0,0,0}, acc1 = {0,0,0,0}, acc2 = {0,0,0,0}, acc3 = {0,0,0,0};

    for (int kc = 0; kc < FIN; kc += 64) {
        __syncthreads();
        for (int i = t; i < 64 * 64 / 4; i += 256)
            reinterpret_cast<float4*>(&wls[0][0])[i] =
                reinterpret_cast<const float4*>(Wc + (size_t)kc * 64)[i];
        for (int rp = 0; rp < 64; rp += 16) {
            int r = rp + (t >> 4);
            int c = (t & 15) * 4;
            int n = n0 + r; if (n >= N) n = N - 1;
            float4 v = reinterpret_cast<const float4*>(x + (size_t)n * FIN + kc)[t & 15];
            xs[c + 0][r] = v.x; xs[c + 1][r] = v.y; xs[c + 2][r] = v.z; xs[c + 3][r] = v.w;
        }
        __syncthreads();
#pragma unroll 8
        for (int k = 0; k < 64; ++k) {
            float4 xv = *reinterpret_cast<const float4*>(&xs[k][tr * 4]);
            float4 wv = *reinterpret_cast<const float4*>(&wls[k][tc * 4]);
            acc0.x = fmaf(xv.x, wv.x, acc0.x); acc0.y = fmaf(xv.x, wv.y, acc0.y);
            acc0.z = fmaf(xv.x, wv.z, acc0.z); acc0.w = fmaf(xv.x, wv.w, acc0.w);
            acc1.x = fmaf(xv.y, wv.x, acc1.x); acc1.y = fmaf(xv.y, wv.y, acc1.y);
            acc1.z = fmaf(xv.y, wv.z, acc1.z); acc1.w = fmaf(xv.y, wv.w, acc1.w);
            acc2.x = fmaf(xv.z, wv.x, acc2.x); acc2.y = fmaf(xv.z, wv.y, acc2.y);
            acc2.z = fmaf(xv.z, wv.z, acc2.z); acc2.w = fmaf(xv.z, wv.w, acc2.w);
            acc3.x = fmaf(xv.w, wv.x, acc3.x); acc3.y = fmaf(xv.w, wv.y, acc3.y);
            acc3.z = fmaf(xv.w, wv.z, acc3.z); acc3.w = fmaf(xv.w, wv.w, acc3.w);
        }
    }
    uint2* bh2 = reinterpret_cast<uint2*>(bh);
    int n;
    n = n0 + tr * 4 + 0;
    if (n < N) bh2[(size_t)n * 16 + tc] =
        make_uint2(f2h2(0.1f*acc0.x, 0.1f*acc0.y), f2h2(0.1f*acc0.z, 0.1f*acc0.w));
    n = n0 + tr * 4 + 1;
    if (n < N) bh2[(size_t)n * 16 + tc] =
        make_uint2(f2h2(0.1f*acc1.x, 0.1f*acc1.y), f2h2(0.1f*acc1.z, 0.1f*acc1.w));
    n = n0 + tr * 4 + 2;
    if (n < N) bh2[(size_t)n * 16 + tc] =
        make_uint2(f2h2(0.1f*acc2.x, 0.1f*acc2.y), f2h2(0.1f*acc2.z, 0.1f*acc2.w));
    n = n0 + tr * 4 + 3;
    if (n < N) bh2[(size_t)n * 16 + tc] =
        make_uint2(f2h2(0.1f*acc3.x, 0.1f*acc3.y), f2h2(0.1f*acc3.z, 0.1f*acc3.w));
}

// ======== bucketed CSR build: 3 passes, XCD-local writes ========
// bucket = dst >> 8 (256 buckets cover dst < 65536)

// Pass A: global bucket counts via per-block LDS histogram
__global__ __launch_bounds__(256) void bucketcnt_kernel(const int* __restrict__ ei,
                                                        int* __restrict__ gcnt, int E) {
    __shared__ int lh[256];
    lh[threadIdx.x] = 0;
    __syncthreads();
    for (int e = blockIdx.x * 256 + threadIdx.x; e < E; e += gridDim.x * 256)
        atomicAdd(&lh[ei[E + e] >> 8], 1);
    __syncthreads();
    if (lh[threadIdx.x]) atomicAdd(&gcnt[threadIdx.x], lh[threadIdx.x]);
}

// scan 256 bucket counts -> goff[0..256], gcur[b]=goff[b]  (one block)
__global__ __launch_bounds__(256) void bscan_kernel(const int* __restrict__ gcnt,
                                                    int* __restrict__ goff,
                                                    int* __restrict__ gcur) {
    __shared__ int sd[256];
    int t = threadIdx.x;
    int c = gcnt[t];
    sd[t] = c;
    __syncthreads();
    for (int o = 1; o < 256; o <<= 1) {
        int v = (t >= o) ? sd[t - o] : 0;
        __syncthreads();
        sd[t] += v;
        __syncthreads();
    }
    int ex = sd[t] - c;          // exclusive
    goff[t] = ex;
    gcur[t] = ex;
    if (t == 255) goff[256] = sd[255];
}

// Pass B: chunk-local count -> contiguous global reservation -> dense u64 writes
constexpr int CHUNK = 4096;      // 256 threads x 16 edges
__global__ __launch_bounds__(256) void bucketsct_kernel(const int* __restrict__ ei,
                                                        const float* __restrict__ ew,
                                                        int* __restrict__ gcur,
                                                        unsigned long long* __restrict__ tmp,
                                                        int E) {
    __shared__ int lh[256], lbase[256], lcur[256];
    const int t = threadIdx.x;
    const int e0 = blockIdx.x * CHUNK;
    lh[t] = 0;
    __syncthreads();
    int myd[16], mys[16];
    unsigned short myw[16];
#pragma unroll
    for (int k = 0; k < 16; ++k) {
        int e = e0 + k * 256 + t;
        if (e < E) {
            int d = ei[E + e];
            myd[k] = d; mys[k] = ei[e]; myw[k] = f2hbits(ew[e]);
            atomicAdd(&lh[d >> 8], 1);
        } else myd[k] = -1;
    }
    __syncthreads();
    if (lh[t]) lbase[t] = atomicAdd(&gcur[t], lh[t]);
    lcur[t] = 0;
    __syncthreads();
#pragma unroll
    for (int k = 0; k < 16; ++k) {
        if (myd[k] >= 0) {
            int bkt = myd[k] >> 8;
            int slot = atomicAdd(&lcur[bkt], 1);
            unsigned long long v = ((unsigned long long)(unsigned)myd[k] << 32)
                                 | ((unsigned long long)myw[k] << 16)
                                 | (unsigned)(mys[k] & 0xffff);
            tmp[(size_t)lbase[bkt] + slot] = v;
        }
    }
}

// Pass C: per-bucket counting sort -> final epk (4B) + row_start
__global__ __launch_bounds__(256) void buildcsr_kernel(const unsigned long long* __restrict__ tmp,
                                                       const int* __restrict__ goff,
                                                       int* __restrict__ row_start,
                                                       unsigned* __restrict__ epk,
                                                       int N, int E) {
    __shared__ int cnt[256], sc[256], pos[256];
    const int b = blockIdx.x;
    const int t = threadIdx.x;
    const int lo = goff[b], hi = goff[b + 1];
    cnt[t] = 0;
    __syncthreads();
    for (int i = lo + t; i < hi; i += 256)
        atomicAdd(&cnt[(int)((tmp[i] >> 32) & 0xff)], 1);
    __syncthreads();
    sc[t] = cnt[t];
    __syncthreads();
    for (int o = 1; o < 256; o <<= 1) {
        int v = (t >= o) ? sc[t - o] : 0;
        __syncthreads();
        sc[t] += v;
        __syncthreads();
    }
    int excl = sc[t] - cnt[t];
    pos[t] = excl;
    int dst = b * 256 + t;
    if (dst < N) row_start[dst] = lo + excl;
    if (b == 0 && t == 0) row_start[N] = E;
    __syncthreads();
    for (int i = lo + t; i < hi; i += 256) {
        unsigned long long v = tmp[i];
        int dl = (int)((v >> 32) & 0xff);
        int p = atomicAdd(&pos[dl], 1);
        epk[lo + p] = (unsigned)(v & 0xffffffffu);
    }
}

// ---------------- one Peaceman-Rachford step (uh-only state) ----------------
// identity: 2*relu(u) - u = |u|  =>  uh = |u| - b ;  un = 2*V(uh) - uh - b
// normal:  s = V(uh_n);  un = 2s - uh_n - b;  out = fp16(|un| - b)
// first :  gather source = bh (uh_0 = -b):  s' = V(b);  un = -2s'
// last  :  out = fp16(relu(un))   (decoder input)
__global__ __launch_bounds__(256) void step_kernel(const uint4* __restrict__ gh,  // gather rows [N*8]
                                                   const uint4* __restrict__ uhr, // own uh row [N*8]
                                                   const uint4* __restrict__ bh,  // b rows [N*8]
                                                   const int* __restrict__ row_start,
                                                   const unsigned* __restrict__ epk,
                                                   uint4* __restrict__ outh,      // uh_next or relu(u)
                                                   int N, int is_first, int is_last) {
    int node = blockIdx.x * 4 + (threadIdx.x >> 6);
    if (node >= N) return;
    int lane = threadIdx.x & 63;
    int sub  = lane >> 3;
    int fo   = lane & 7;
    size_t r8 = (size_t)node * 8 + fo;

    // issue-early: own-row loads before the gather loop (latency hides under gathers)
    uint4 bvv = {0,0,0,0}, uvv = {0,0,0,0};
    if (lane < 8) {
        bvv = bh[r8];
        uvv = uhr[r8];
    }

    int e0 = row_start[node];
    int e1 = row_start[node + 1];

    float a0[8] = {0,0,0,0,0,0,0,0};
    float a1[8] = {0,0,0,0,0,0,0,0};
    int e = e0 + sub;
    for (; e + 8 < e1; e += 16) {
        unsigned p0 = epk[e];
        unsigned p1 = epk[e + 8];
        int s0 = (int)(p0 & 0xffffu);
        int s1 = (int)(p1 & 0xffffu);
        union { unsigned short us; __half h; } w0c, w1c;
        w0c.us = (unsigned short)(p0 >> 16);
        w1c.us = (unsigned short)(p1 >> 16);
        float w0 = __half2float(w0c.h);
        float w1 = __half2float(w1c.h);
        uint4 v0 = gh[(size_t)s0 * 8 + fo];
        uint4 v1 = gh[(size_t)s1 * 8 + fo];
        fma8(v0, w0, a0);
        fma8(v1, w1, a1);
    }
    if (e < e1) {
        unsigned p0 = epk[e];
        int s0 = (int)(p0 & 0xffffu);
        union { unsigned short us; __half h; } w0c;
        w0c.us = (unsigned short)(p0 >> 16);
        float w0 = __half2float(w0c.h);
        uint4 v0 = gh[(size_t)s0 * 8 + fo];
        fma8(v0, w0, a0);
    }
    float s[8];
#pragma unroll
    for (int i = 0; i < 8; ++i) {
        float v = a0[i] + a1[i];
        v += __shfl_xor(v, 8);
        v += __shfl_xor(v, 16);
        v += __shfl_xor(v, 32);
        s[i] = v;
    }

    if (lane < 8) {   // sub == 0; fo == lane
        float bf[8];
        unpack8(bvv, bf);
        float un[8];
        if (is_first) {
#pragma unroll
            for (int i = 0; i < 8; ++i) un[i] = -2.f * s[i];
        } else {
            float uhv[8];
            unpack8(uvv, uhv);
#pragma unroll
            for (int i = 0; i < 8; ++i)
                un[i] = 2.f * s[i] - uhv[i] - bf[i];
        }
        float ov[8];
        if (is_last) {
#pragma unroll
            for (int i = 0; i < 8; ++i) ov[i] = fmaxf(un[i], 0.f);
        } else {
#pragma unroll
            for (int i = 0; i < 8; ++i) ov[i] = fabsf(un[i]) - bf[i];
        }
        uint4 oh;
        oh.x = f2h2(ov[0], ov[1]); oh.y = f2h2(ov[2], ov[3]);
        oh.z = f2h2(ov[4], ov[5]); oh.w = f2h2(ov[6], ov[7]);
        outh[r8] = oh;
    }
}

// ------------- out = rh @ W_dec, rh already relu'd fp16 (register-tiled 4x4) -------------
__global__ __launch_bounds__(256) void dec_kernel(const uint4* __restrict__ rh,
                                                  const float* __restrict__ Wd,
                                                  float* __restrict__ out, int N) {
    __shared__ float xs[64][68];    // transposed rh chunk
    __shared__ float wls[64][64];
    const int t  = threadIdx.x;
    const int tr = t >> 4;
    const int tc = t & 15;
    const int n0 = blockIdx.x * 64;

    for (int i = t; i < 64 * 64 / 4; i += 256)
        reinterpret_cast<float4*>(&wls[0][0])[i] = reinterpret_cast<const float4*>(Wd)[i];
    for (int rp = 0; rp < 64; rp += 32) {
        int r = rp + (t >> 3);
        int c = (t & 7) * 8;
        int n = n0 + r; if (n >= N) n = N - 1;
        uint4 v = rh[(size_t)n * 8 + (t & 7)];
        float f[8];
        unpack8(v, f);
#pragma unroll
        for (int i = 0; i < 8; ++i) xs[c + i][r] = f[i];
    }
    __syncthreads();

    float4 acc0 = {0,0,0,0}, acc1 = {0,0,0,0}, acc2 = {0,0,0,0}, acc3 = {0,0,0,0};
#pragma unroll 8
    for (int k = 0; k < 64; ++k) {
        float4 xv = *reinterpret_cast<const float4*>(&xs[k][tr * 4]);
        float4 wv = *reinterpret_cast<const float4*>(&wls[k][tc * 4]);
        acc0.x = fmaf(xv.x, wv.x, acc0.x); acc0.y = fmaf(xv.x, wv.y, acc0.y);
        acc0.z = fmaf(xv.x, wv.z, acc0.z); acc0.w = fmaf(xv.x, wv.w, acc0.w);
        acc1.x = fmaf(xv.y, wv.x, acc1.x); acc1.y = fmaf(xv.y, wv.y, acc1.y);
        acc1.z = fmaf(xv.y, wv.z, acc1.z); acc1.w = fmaf(xv.y, wv.w, acc1.w);
        acc2.x = fmaf(xv.z, wv.x, acc2.x); acc2.y = fmaf(xv.z, wv.y, acc2.y);
        acc2.z = fmaf(xv.z, wv.z, acc2.z); acc2.w = fmaf(xv.z, wv.w, acc2.w);
        acc3.x = fmaf(xv.w, wv.x, acc3.x); acc3.y = fmaf(xv.w, wv.y, acc3.y);
        acc3.z = fmaf(xv.w, wv.z, acc3.z); acc3.w = fmaf(xv.w, wv.w, acc3.w);
    }
    int n;
    n = n0 + tr * 4 + 0;
    if (n < N) reinterpret_cast<float4*>(out + (size_t)n * 64)[tc] = acc0;
    n = n0 + tr * 4 + 1;
    if (n < N) reinterpret_cast<float4*>(out + (size_t)n * 64)[tc] = acc1;
    n = n0 + tr * 4 + 2;
    if (n < N) reinterpret_cast<float4*>(out + (size_t)n * 64)[tc] = acc2;
    n = n0 + tr * 4 + 3;
    if (n < N) reinterpret_cast<float4*>(out + (size_t)n * 64)[tc] = acc3;
}

extern "C" void kernel_launch(void* const* d_in, const int* in_sizes, int n_in,
                              void* d_out, int out_size, void* d_ws, size_t ws_size,
                              hipStream_t stream) {
    const float* x  = (const float*)d_in[0];
    const int*   ei = (const int*)d_in[1];
    const float* ew = (const float*)d_in[2];
    const float* We = (const float*)d_in[3];
    const float* Wb = (const float*)d_in[4];
    const float* Wd = (const float*)d_in[5];
    float* out = (float*)d_out;

    const int N = in_sizes[0] / FIN;
    const int E = in_sizes[2];

    char* ws = (char*)d_ws;
    size_t off = 0;
    auto alloc = [&](size_t bytes) -> void* {
        void* p = ws + off;
        off = (off + bytes + 255) & ~(size_t)255;
        return p;
    };
    const size_t nodef16 = (size_t)N * H * sizeof(unsigned short);
    unsigned short* bh   = (unsigned short*)alloc(nodef16);
    unsigned short* uhha = (unsigned short*)alloc(nodef16);
    unsigned short* uhhb = (unsigned short*)alloc(nodef16);
    float* Wc   = (float*)alloc((size_t)FIN * H * sizeof(float));
    int*   rsrt = (int*)alloc((size_t)(N + 1) * sizeof(int));
    int*   gcnt = (int*)alloc(256 * sizeof(int));
    int*   goff = (int*)alloc(257 * sizeof(int));
    int*   gcur = (int*)alloc(256 * sizeof(int));
    unsigned long long* tmp = (unsigned long long*)alloc((size_t)E * sizeof(unsigned long long));
    unsigned* epk = (unsigned*)alloc((size_t)E * sizeof(unsigned));

    // ---- CSR build (bucketed counting sort) ----
    hipMemsetAsync(gcnt, 0, 256 * sizeof(int), stream);
    bucketcnt_kernel<<<256, 256, 0, stream>>>(ei, gcnt, E);
    bscan_kernel<<<1, 256, 0, stream>>>(gcnt, goff, gcur);
    bucketsct_kernel<<<(E + CHUNK - 1) / CHUNK, 256, 0, stream>>>(ei, ew, gcur, tmp, E);
    const int nbk = (N + 255) >> 8;
    buildcsr_kernel<<<nbk, 256, 0, stream>>>(tmp, goff, rsrt, epk, N, E);

    // ---- encoder path: only b (fp16) is materialized ----
    wc_kernel<<<FIN * H / 256, 256, 0, stream>>>(We, Wb, Wc);
    benc_kernel<<<(N + 63) / 64, 256, 0, stream>>>(x, Wc, bh, N);

    const int sgrid = (N + 3) / 4;
    // first step: uh_0 = -b handled by gathering bh with sign flip
    step_kernel<<<sgrid, 256, 0, stream>>>((const uint4*)bh, (const uint4*)bh, (const uint4*)bh,
                                           rsrt, epk, (uint4*)uhha, N, 1, 0);
    unsigned short *uhcur = uhha, *uhnext = uhhb;
    for (int it = 1; it < NIT; ++it) {
        int last = (it == NIT - 1) ? 1 : 0;
        step_kernel<<<sgrid, 256, 0, stream>>>((const uint4*)uhcur, (const uint4*)uhcur,
                                               (const uint4*)bh, rsrt, epk,
                                               (uint4*)uhnext, N, 0, last);
        unsigned short* th;
        th = uhcur; uhcur = uhnext; uhnext = th;
    }

    // uhcur now holds fp16 relu(u_20)
    dec_kernel<<<(N + 63) / 64, 256, 0, stream>>>((const uint4*)uhcur, Wd, out, N);
}

// Round 6
// 469.358 us; speedup vs baseline: 2.8627x; 1.1341x over previous
//
#include <hip/hip_runtime.h>
#include <hip/hip_fp16.h>

constexpr int H    = 64;     // hidden/out features
constexpr int FIN  = 256;    // input features
constexpr int NIT  = 20;     // fixed-point iterations
// ALPHA = 0.1 folded into benc kernel

__device__ __forceinline__ unsigned f2h2(float a, float b) {
    union { unsigned u; __half2 h; } c;
    c.h = __floats2half2_rn(a, b);
    return c.u;
}

__device__ __forceinline__ unsigned short f2hbits(float a) {
    union { __half h; unsigned short us; } c;
    c.h = __float2half_rn(a);
    return c.us;
}

// high 16 bits of packed edge word -> float weight
__device__ __forceinline__ float hw(unsigned p) {
    union { unsigned short us; __half h; } c;
    c.us = (unsigned short)(p >> 16);
    return __half2float(c.h);
}

// uint2 = 4 fp16; acc[i] += w * v[i]
__device__ __forceinline__ void fma4h(const uint2& v, float w, float* acc) {
    union { unsigned u; __half2 h; } c0, c1;
    c0.u = v.x; c1.u = v.y;
    float2 f0 = __half22float2(c0.h), f1 = __half22float2(c1.h);
    acc[0] = fmaf(w, f0.x, acc[0]); acc[1] = fmaf(w, f0.y, acc[1]);
    acc[2] = fmaf(w, f1.x, acc[2]); acc[3] = fmaf(w, f1.y, acc[3]);
}

__device__ __forceinline__ void unpack4(const uint2& v, float* f) {
    union { unsigned u; __half2 h; } c0, c1;
    c0.u = v.x; c1.u = v.y;
    float2 f0 = __half22float2(c0.h), f1 = __half22float2(c1.h);
    f[0] = f0.x; f[1] = f0.y; f[2] = f1.x; f[3] = f1.y;
}

// ---------------- Wc = W_enc @ W_bias  [FIN x H] ----------------
__global__ __launch_bounds__(256) void wc_kernel(const float* __restrict__ We,
                                                 const float* __restrict__ Wb,
                                                 float* __restrict__ Wc) {
    __shared__ float wb[H * H];
    for (int i = threadIdx.x; i < H * H / 4; i += 256)
        reinterpret_cast<float4*>(wb)[i] = reinterpret_cast<const float4*>(Wb)[i];
    __syncthreads();
    int idx = blockIdx.x * 256 + threadIdx.x;    // 0 .. FIN*H-1
    int i = idx >> 6, j = idx & 63;
    float acc = 0.f;
#pragma unroll 8
    for (int k = 0; k < H; ++k) acc += We[i * H + k] * wb[k * H + j];
    Wc[i * H + j] = acc;
}

// ------------- b_h = fp16( 0.1 * x @ Wc )  (register-tiled 4x4) -------------
__global__ __launch_bounds__(256) void benc_kernel(const float* __restrict__ x,
                                                   const float* __restrict__ Wc,
                                                   unsigned short* __restrict__ bh, int N) {
    __shared__ float xs[64][68];    // transposed x chunk: xs[k][r]
    __shared__ float wls[64][64];   // Wc chunk: wls[k][j]
    const int t  = threadIdx.x;
    const int tr = t >> 4;          // 0..15 row-group
    const int tc = t & 15;          // 0..15 col-group
    const int n0 = blockIdx.x * 64;

    float4 acc0 = {0,0,0,0}, acc1 = {0,0,0,0}, acc2 = {0,0,0,0}, acc3 = {0,0,0,0};

    for (int kc = 0; kc < FIN; kc += 64) {
        __syncthreads();
        for (int i = t; i < 64 * 64 / 4; i += 256)
            reinterpret_cast<float4*>(&wls[0][0])[i] =
                reinterpret_cast<const float4*>(Wc + (size_t)kc * 64)[i];
        // stage x chunk transposed; lane assignment r=(t&15) -> 16 consecutive
        // rows written simultaneously -> banks 0..15/16..31, 2-way max (free)
        for (int rp = 0; rp < 64; rp += 16) {
            int r = rp + (t & 15);
            int j = t >> 4;          // column quad 0..15
            int c = j * 4;
            int n = n0 + r; if (n >= N) n = N - 1;
            float4 v = reinterpret_cast<const float4*>(x + (size_t)n * FIN + kc)[j];
            xs[c + 0][r] = v.x; xs[c + 1][r] = v.y; xs[c + 2][r] = v.z; xs[c + 3][r] = v.w;
        }
        __syncthreads();
#pragma unroll 8
        for (int k = 0; k < 64; ++k) {
            float4 xv = *reinterpret_cast<const float4*>(&xs[k][tr * 4]);
            float4 wv = *reinterpret_cast<const float4*>(&wls[k][tc * 4]);
            acc0.x = fmaf(xv.x, wv.x, acc0.x); acc0.y = fmaf(xv.x, wv.y, acc0.y);
            acc0.z = fmaf(xv.x, wv.z, acc0.z); acc0.w = fmaf(xv.x, wv.w, acc0.w);
            acc1.x = fmaf(xv.y, wv.x, acc1.x); acc1.y = fmaf(xv.y, wv.y, acc1.y);
            acc1.z = fmaf(xv.y, wv.z, acc1.z); acc1.w = fmaf(xv.y, wv.w, acc1.w);
            acc2.x = fmaf(xv.z, wv.x, acc2.x); acc2.y = fmaf(xv.z, wv.y, acc2.y);
            acc2.z = fmaf(xv.z, wv.z, acc2.z); acc2.w = fmaf(xv.z, wv.w, acc2.w);
            acc3.x = fmaf(xv.w, wv.x, acc3.x); acc3.y = fmaf(xv.w, wv.y, acc3.y);
            acc3.z = fmaf(xv.w, wv.z, acc3.z); acc3.w = fmaf(xv.w, wv.w, acc3.w);
        }
    }
    uint2* bh2 = reinterpret_cast<uint2*>(bh);
    int n;
    n = n0 + tr * 4 + 0;
    if (n < N) bh2[(size_t)n * 16 + tc] =
        make_uint2(f2h2(0.1f*acc0.x, 0.1f*acc0.y), f2h2(0.1f*acc0.z, 0.1f*acc0.w));
    n = n0 + tr * 4 + 1;
    if (n < N) bh2[(size_t)n * 16 + tc] =
        make_uint2(f2h2(0.1f*acc1.x, 0.1f*acc1.y), f2h2(0.1f*acc1.z, 0.1f*acc1.w));
    n = n0 + tr * 4 + 2;
    if (n < N) bh2[(size_t)n * 16 + tc] =
        make_uint2(f2h2(0.1f*acc2.x, 0.1f*acc2.y), f2h2(0.1f*acc2.z, 0.1f*acc2.w));
    n = n0 + tr * 4 + 3;
    if (n < N) bh2[(size_t)n * 16 + tc] =
        make_uint2(f2h2(0.1f*acc3.x, 0.1f*acc3.y), f2h2(0.1f*acc3.z, 0.1f*acc3.w));
}

// ======== bucketed CSR build: 3 passes, XCD-local writes ========
// bucket = dst >> 8 (256 buckets cover dst < 65536)

__global__ __launch_bounds__(256) void bucketcnt_kernel(const int* __restrict__ ei,
                                                        int* __restrict__ gcnt, int E) {
    __shared__ int lh[256];
    lh[threadIdx.x] = 0;
    __syncthreads();
    for (int e = blockIdx.x * 256 + threadIdx.x; e < E; e += gridDim.x * 256)
        atomicAdd(&lh[ei[E + e] >> 8], 1);
    __syncthreads();
    if (lh[threadIdx.x]) atomicAdd(&gcnt[threadIdx.x], lh[threadIdx.x]);
}

__global__ __launch_bounds__(256) void bscan_kernel(const int* __restrict__ gcnt,
                                                    int* __restrict__ goff,
                                                    int* __restrict__ gcur) {
    __shared__ int sd[256];
    int t = threadIdx.x;
    int c = gcnt[t];
    sd[t] = c;
    __syncthreads();
    for (int o = 1; o < 256; o <<= 1) {
        int v = (t >= o) ? sd[t - o] : 0;
        __syncthreads();
        sd[t] += v;
        __syncthreads();
    }
    int ex = sd[t] - c;          // exclusive
    goff[t] = ex;
    gcur[t] = ex;
    if (t == 255) goff[256] = sd[255];
}

constexpr int CHUNK = 4096;      // 256 threads x 16 edges
__global__ __launch_bounds__(256) void bucketsct_kernel(const int* __restrict__ ei,
                                                        const float* __restrict__ ew,
                                                        int* __restrict__ gcur,
                                                        unsigned long long* __restrict__ tmp,
                                                        int E) {
    __shared__ int lh[256], lbase[256], lcur[256];
    const int t = threadIdx.x;
    const int e0 = blockIdx.x * CHUNK;
    lh[t] = 0;
    __syncthreads();
    int myd[16], mys[16];
    unsigned short myw[16];
#pragma unroll
    for (int k = 0; k < 16; ++k) {
        int e = e0 + k * 256 + t;
        if (e < E) {
            int d = ei[E + e];
            myd[k] = d; mys[k] = ei[e]; myw[k] = f2hbits(ew[e]);
            atomicAdd(&lh[d >> 8], 1);
        } else myd[k] = -1;
    }
    __syncthreads();
    if (lh[t]) lbase[t] = atomicAdd(&gcur[t], lh[t]);
    lcur[t] = 0;
    __syncthreads();
#pragma unroll
    for (int k = 0; k < 16; ++k) {
        if (myd[k] >= 0) {
            int bkt = myd[k] >> 8;
            int slot = atomicAdd(&lcur[bkt], 1);
            unsigned long long v = ((unsigned long long)(unsigned)myd[k] << 32)
                                 | ((unsigned long long)myw[k] << 16)
                                 | (unsigned)(mys[k] & 0xffff);
            tmp[(size_t)lbase[bkt] + slot] = v;
        }
    }
}

__global__ __launch_bounds__(256) void buildcsr_kernel(const unsigned long long* __restrict__ tmp,
                                                       const int* __restrict__ goff,
                                                       int* __restrict__ row_start,
                                                       unsigned* __restrict__ epk,
                                                       int N, int E) {
    __shared__ int cnt[256], sc[256], pos[256];
    const int b = blockIdx.x;
    const int t = threadIdx.x;
    const int lo = goff[b], hi = goff[b + 1];
    cnt[t] = 0;
    __syncthreads();
    for (int i = lo + t; i < hi; i += 256)
        atomicAdd(&cnt[(int)((tmp[i] >> 32) & 0xff)], 1);
    __syncthreads();
    sc[t] = cnt[t];
    __syncthreads();
    for (int o = 1; o < 256; o <<= 1) {
        int v = (t >= o) ? sc[t - o] : 0;
        __syncthreads();
        sc[t] += v;
        __syncthreads();
    }
    int excl = sc[t] - cnt[t];
    pos[t] = excl;
    int dst = b * 256 + t;
    if (dst < N) row_start[dst] = lo + excl;
    if (b == 0 && t == 0) row_start[N] = E;
    __syncthreads();
    for (int i = lo + t; i < hi; i += 256) {
        unsigned long long v = tmp[i];
        int dl = (int)((v >> 32) & 0xff);
        int p = atomicAdd(&pos[dl], 1);
        epk[lo + p] = (unsigned)(v & 0xffffffffu);
    }
}

// ---------------- one Peaceman-Rachford step (uh-only state) ----------------
// identity: 2*relu(u) - u = |u|  =>  uh = |u| - b ;  un = 2*V(uh) - uh - b
// normal:  s = V(uh_n);  un = 2s - uh_n - b;  out = fp16(|un| - b)
// first :  gather source = bh (uh_0 = -b):  s' = V(b);  un = -2s'
// last  :  out = fp16(relu(un))   (decoder input)
// layout: 16 lanes per node (lane owns 4 features = uint2), 4 nodes per wave.
// Edge sum is sequential in-register -> NO cross-lane reduce; 4 unrolled
// accumulator chains give 16 outstanding gathers per wave.
__global__ __launch_bounds__(256) void step_kernel(const uint2* __restrict__ gh,  // gather rows [N*16]
                                                   const uint2* __restrict__ uhr, // own uh rows [N*16]
                                                   const uint2* __restrict__ bh,  // b rows [N*16]
                                                   const int* __restrict__ row_start,
                                                   const unsigned* __restrict__ epk,
                                                   uint2* __restrict__ outh,      // uh_next or relu(u)
                                                   int N, int is_first, int is_last) {
    const int wid  = threadIdx.x >> 6;
    const int lane = threadIdx.x & 63;
    const int g    = lane >> 4;                   // node group within wave
    const int fq   = lane & 15;                   // uint2 index within row
    const int node = (blockIdx.x * 4 + wid) * 4 + g;
    if (node >= N) return;
    const size_t r16 = (size_t)node * 16 + fq;

    // issue-early: own-row loads hide under the gather loop
    uint2 bvv = bh[r16];
    uint2 uvv = uhr[r16];

    const int e0 = row_start[node];
    const int e1 = row_start[node + 1];

    float a0[4] = {0,0,0,0}, a1[4] = {0,0,0,0};
    float a2[4] = {0,0,0,0}, a3[4] = {0,0,0,0};
    int e = e0;
    for (; e + 4 <= e1; e += 4) {
        unsigned p0 = epk[e];
        unsigned p1 = epk[e + 1];
        unsigned p2 = epk[e + 2];
        unsigned p3 = epk[e + 3];
        uint2 v0 = gh[(size_t)(p0 & 0xffffu) * 16 + fq];
        uint2 v1 = gh[(size_t)(p1 & 0xffffu) * 16 + fq];
        uint2 v2 = gh[(size_t)(p2 & 0xffffu) * 16 + fq];
        uint2 v3 = gh[(size_t)(p3 & 0xffffu) * 16 + fq];
        fma4h(v0, hw(p0), a0);
        fma4h(v1, hw(p1), a1);
        fma4h(v2, hw(p2), a2);
        fma4h(v3, hw(p3), a3);
    }
    for (; e < e1; ++e) {
        unsigned p0 = epk[e];
        uint2 v0 = gh[(size_t)(p0 & 0xffffu) * 16 + fq];
        fma4h(v0, hw(p0), a0);
    }
    float s[4];
#pragma unroll
    for (int i = 0; i < 4; ++i) s[i] = (a0[i] + a1[i]) + (a2[i] + a3[i]);

    float bf[4];
    unpack4(bvv, bf);
    float un[4];
    if (is_first) {
#pragma unroll
        for (int i = 0; i < 4; ++i) un[i] = -2.f * s[i];
    } else {
        float uhv[4];
        unpack4(uvv, uhv);
#pragma unroll
        for (int i = 0; i < 4; ++i) un[i] = 2.f * s[i] - uhv[i] - bf[i];
    }
    float ov[4];
    if (is_last) {
#pragma unroll
        for (int i = 0; i < 4; ++i) ov[i] = fmaxf(un[i], 0.f);
    } else {
#pragma unroll
        for (int i = 0; i < 4; ++i) ov[i] = fabsf(un[i]) - bf[i];
    }
    outh[r16] = make_uint2(f2h2(ov[0], ov[1]), f2h2(ov[2], ov[3]));
}

// ------------- out = rh @ W_dec, rh already relu'd fp16 (register-tiled 4x4) -------------
__global__ __launch_bounds__(256) void dec_kernel(const uint2* __restrict__ rh2,
                                                  const float* __restrict__ Wd,
                                                  float* __restrict__ out, int N) {
    __shared__ float xs[64][68];    // transposed rh chunk
    __shared__ float wls[64][64];
    const int t  = threadIdx.x;
    const int tr = t >> 4;
    const int tc = t & 15;
    const int n0 = blockIdx.x * 64;

    for (int i = t; i < 64 * 64 / 4; i += 256)
        reinterpret_cast<float4*>(&wls[0][0])[i] = reinterpret_cast<const float4*>(Wd)[i];
    // conflict-free staging: 16 simultaneous writers hit 16 consecutive rows
    for (int rp = 0; rp < 64; rp += 16) {
        int r = rp + (t & 15);
        int j = t >> 4;              // uint2 index 0..15
        int c = j * 4;
        int n = n0 + r; if (n >= N) n = N - 1;
        uint2 v = rh2[(size_t)n * 16 + j];
        float f[4];
        unpack4(v, f);
#pragma unroll
        for (int i = 0; i < 4; ++i) xs[c + i][r] = f[i];
    }
    __syncthreads();

    float4 acc0 = {0,0,0,0}, acc1 = {0,0,0,0}, acc2 = {0,0,0,0}, acc3 = {0,0,0,0};
#pragma unroll 8
    for (int k = 0; k < 64; ++k) {
        float4 xv = *reinterpret_cast<const float4*>(&xs[k][tr * 4]);
        float4 wv = *reinterpret_cast<const float4*>(&wls[k][tc * 4]);
        acc0.x = fmaf(xv.x, wv.x, acc0.x); acc0.y = fmaf(xv.x, wv.y, acc0.y);
        acc0.z = fmaf(xv.x, wv.z, acc0.z); acc0.w = fmaf(xv.x, wv.w, acc0.w);
        acc1.x = fmaf(xv.y, wv.x, acc1.x); acc1.y = fmaf(xv.y, wv.y, acc1.y);
        acc1.z = fmaf(xv.y, wv.z, acc1.z); acc1.w = fmaf(xv.y, wv.w, acc1.w);
        acc2.x = fmaf(xv.z, wv.x, acc2.x); acc2.y = fmaf(xv.z, wv.y, acc2.y);
        acc2.z = fmaf(xv.z, wv.z, acc2.z); acc2.w = fmaf(xv.z, wv.w, acc2.w);
        acc3.x = fmaf(xv.w, wv.x, acc3.x); acc3.y = fmaf(xv.w, wv.y, acc3.y);
        acc3.z = fmaf(xv.w, wv.z, acc3.z); acc3.w = fmaf(xv.w, wv.w, acc3.w);
    }
    int n;
    n = n0 + tr * 4 + 0;
    if (n < N) reinterpret_cast<float4*>(out + (size_t)n * 64)[tc] = acc0;
    n = n0 + tr * 4 + 1;
    if (n < N) reinterpret_cast<float4*>(out + (size_t)n * 64)[tc] = acc1;
    n = n0 + tr * 4 + 2;
    if (n < N) reinterpret_cast<float4*>(out + (size_t)n * 64)[tc] = acc2;
    n = n0 + tr * 4 + 3;
    if (n < N) reinterpret_cast<float4*>(out + (size_t)n * 64)[tc] = acc3;
}

extern "C" void kernel_launch(void* const* d_in, const int* in_sizes, int n_in,
                              void* d_out, int out_size, void* d_ws, size_t ws_size,
                              hipStream_t stream) {
    const float* x  = (const float*)d_in[0];
    const int*   ei = (const int*)d_in[1];
    const float* ew = (const float*)d_in[2];
    const float* We = (const float*)d_in[3];
    const float* Wb = (const float*)d_in[4];
    const float* Wd = (const float*)d_in[5];
    float* out = (float*)d_out;

    const int N = in_sizes[0] / FIN;
    const int E = in_sizes[2];

    char* ws = (char*)d_ws;
    size_t off = 0;
    auto alloc = [&](size_t bytes) -> void* {
        void* p = ws + off;
        off = (off + bytes + 255) & ~(size_t)255;
        return p;
    };
    const size_t nodef16 = (size_t)N * H * sizeof(unsigned short);
    unsigned short* bh   = (unsigned short*)alloc(nodef16);
    unsigned short* uhha = (unsigned short*)alloc(nodef16);
    unsigned short* uhhb = (unsigned short*)alloc(nodef16);
    float* Wc   = (float*)alloc((size_t)FIN * H * sizeof(float));
    int*   rsrt = (int*)alloc((size_t)(N + 1) * sizeof(int));
    int*   gcnt = (int*)alloc(256 * sizeof(int));
    int*   goff = (int*)alloc(257 * sizeof(int));
    int*   gcur = (int*)alloc(256 * sizeof(int));
    unsigned long long* tmp = (unsigned long long*)alloc((size_t)E * sizeof(unsigned long long));
    unsigned* epk = (unsigned*)alloc((size_t)E * sizeof(unsigned));

    // ---- CSR build (bucketed counting sort) ----
    hipMemsetAsync(gcnt, 0, 256 * sizeof(int), stream);
    bucketcnt_kernel<<<256, 256, 0, stream>>>(ei, gcnt, E);
    bscan_kernel<<<1, 256, 0, stream>>>(gcnt, goff, gcur);
    bucketsct_kernel<<<(E + CHUNK - 1) / CHUNK, 256, 0, stream>>>(ei, ew, gcur, tmp, E);
    const int nbk = (N + 255) >> 8;
    buildcsr_kernel<<<nbk, 256, 0, stream>>>(tmp, goff, rsrt, epk, N, E);

    // ---- encoder path: only b (fp16) is materialized ----
    wc_kernel<<<FIN * H / 256, 256, 0, stream>>>(We, Wb, Wc);
    benc_kernel<<<(N + 63) / 64, 256, 0, stream>>>(x, Wc, bh, N);

    const int sgrid = (N + 15) / 16;   // 16 nodes per block (4 waves x 4 nodes)
    // first step: uh_0 = -b handled by gathering bh with sign flip
    step_kernel<<<sgrid, 256, 0, stream>>>((const uint2*)bh, (const uint2*)bh, (const uint2*)bh,
                                           rsrt, epk, (uint2*)uhha, N, 1, 0);
    unsigned short *uhcur = uhha, *uhnext = uhhb;
    for (int it = 1; it < NIT; ++it) {
        int last = (it == NIT - 1) ? 1 : 0;
        step_kernel<<<sgrid, 256, 0, stream>>>((const uint2*)uhcur, (const uint2*)uhcur,
                                               (const uint2*)bh, rsrt, epk,
                                               (uint2*)uhnext, N, 0, last);
        unsigned short* th;
        th = uhcur; uhcur = uhnext; uhnext = th;
    }

    // uhcur now holds fp16 relu(u_20)
    dec_kernel<<<(N + 63) / 64, 256, 0, stream>>>((const uint2*)uhcur, Wd, out, N);
}

// Round 7
// 396.537 us; speedup vs baseline: 3.3884x; 1.1836x over previous
//
#include <hip/hip_runtime.h>
#include <hip/hip_fp16.h>

constexpr int H    = 64;     // hidden/out features
constexpr int FIN  = 256;    // input features
constexpr int NIT  = 20;     // fixed-point iterations
// ALPHA = 0.1 folded into benc kernel

__device__ __forceinline__ unsigned f2h2(float a, float b) {
    union { unsigned u; __half2 h; } c;
    c.h = __floats2half2_rn(a, b);
    return c.u;
}

__device__ __forceinline__ unsigned short f2hbits(float a) {
    union { __half h; unsigned short us; } c;
    c.h = __float2half_rn(a);
    return c.us;
}

// high 16 bits of packed edge word -> float weight
__device__ __forceinline__ float hw(unsigned p) {
    union { unsigned short us; __half h; } c;
    c.us = (unsigned short)(p >> 16);
    return __half2float(c.h);
}

// uint2 = 4 fp16; acc[i] += w * v[i]
__device__ __forceinline__ void fma4h(const uint2& v, float w, float* acc) {
    union { unsigned u; __half2 h; } c0, c1;
    c0.u = v.x; c1.u = v.y;
    float2 f0 = __half22float2(c0.h), f1 = __half22float2(c1.h);
    acc[0] = fmaf(w, f0.x, acc[0]); acc[1] = fmaf(w, f0.y, acc[1]);
    acc[2] = fmaf(w, f1.x, acc[2]); acc[3] = fmaf(w, f1.y, acc[3]);
}

__device__ __forceinline__ void unpack4(const uint2& v, float* f) {
    union { unsigned u; __half2 h; } c0, c1;
    c0.u = v.x; c1.u = v.y;
    float2 f0 = __half22float2(c0.h), f1 = __half22float2(c1.h);
    f[0] = f0.x; f[1] = f0.y; f[2] = f1.x; f[3] = f1.y;
}

// ---------------- Wc = W_enc @ W_bias  [FIN x H] ----------------
__global__ __launch_bounds__(256) void wc_kernel(const float* __restrict__ We,
                                                 const float* __restrict__ Wb,
                                                 float* __restrict__ Wc) {
    __shared__ float wb[H * H];
    for (int i = threadIdx.x; i < H * H / 4; i += 256)
        reinterpret_cast<float4*>(wb)[i] = reinterpret_cast<const float4*>(Wb)[i];
    __syncthreads();
    int idx = blockIdx.x * 256 + threadIdx.x;    // 0 .. FIN*H-1
    int i = idx >> 6, j = idx & 63;
    float acc = 0.f;
#pragma unroll 8
    for (int k = 0; k < H; ++k) acc += We[i * H + k] * wb[k * H + j];
    Wc[i * H + j] = acc;
}

// ------------- b_h = fp16( 0.1 * x @ Wc )  (register-tiled 4x4) -------------
__global__ __launch_bounds__(256) void benc_kernel(const float* __restrict__ x,
                                                   const float* __restrict__ Wc,
                                                   unsigned short* __restrict__ bh, int N) {
    __shared__ float xs[64][68];    // transposed x chunk: xs[k][r]
    __shared__ float wls[64][64];   // Wc chunk: wls[k][j]
    const int t  = threadIdx.x;
    const int tr = t >> 4;          // 0..15 row-group
    const int tc = t & 15;          // 0..15 col-group
    const int n0 = blockIdx.x * 64;

    float4 acc0 = {0,0,0,0}, acc1 = {0,0,0,0}, acc2 = {0,0,0,0}, acc3 = {0,0,0,0};

    for (int kc = 0; kc < FIN; kc += 64) {
        __syncthreads();
        for (int i = t; i < 64 * 64 / 4; i += 256)
            reinterpret_cast<float4*>(&wls[0][0])[i] =
                reinterpret_cast<const float4*>(Wc + (size_t)kc * 64)[i];
        // stage x chunk transposed; 16 consecutive rows written simultaneously
        for (int rp = 0; rp < 64; rp += 16) {
            int r = rp + (t & 15);
            int j = t >> 4;          // column quad 0..15
            int c = j * 4;
            int n = n0 + r; if (n >= N) n = N - 1;
            float4 v = reinterpret_cast<const float4*>(x + (size_t)n * FIN + kc)[j];
            xs[c + 0][r] = v.x; xs[c + 1][r] = v.y; xs[c + 2][r] = v.z; xs[c + 3][r] = v.w;
        }
        __syncthreads();
#pragma unroll 8
        for (int k = 0; k < 64; ++k) {
            float4 xv = *reinterpret_cast<const float4*>(&xs[k][tr * 4]);
            float4 wv = *reinterpret_cast<const float4*>(&wls[k][tc * 4]);
            acc0.x = fmaf(xv.x, wv.x, acc0.x); acc0.y = fmaf(xv.x, wv.y, acc0.y);
            acc0.z = fmaf(xv.x, wv.z, acc0.z); acc0.w = fmaf(xv.x, wv.w, acc0.w);
            acc1.x = fmaf(xv.y, wv.x, acc1.x); acc1.y = fmaf(xv.y, wv.y, acc1.y);
            acc1.z = fmaf(xv.y, wv.z, acc1.z); acc1.w = fmaf(xv.y, wv.w, acc1.w);
            acc2.x = fmaf(xv.z, wv.x, acc2.x); acc2.y = fmaf(xv.z, wv.y, acc2.y);
            acc2.z = fmaf(xv.z, wv.z, acc2.z); acc2.w = fmaf(xv.z, wv.w, acc2.w);
            acc3.x = fmaf(xv.w, wv.x, acc3.x); acc3.y = fmaf(xv.w, wv.y, acc3.y);
            acc3.z = fmaf(xv.w, wv.z, acc3.z); acc3.w = fmaf(xv.w, wv.w, acc3.w);
        }
    }
    uint2* bh2 = reinterpret_cast<uint2*>(bh);
    int n;
    n = n0 + tr * 4 + 0;
    if (n < N) bh2[(size_t)n * 16 + tc] =
        make_uint2(f2h2(0.1f*acc0.x, 0.1f*acc0.y), f2h2(0.1f*acc0.z, 0.1f*acc0.w));
    n = n0 + tr * 4 + 1;
    if (n < N) bh2[(size_t)n * 16 + tc] =
        make_uint2(f2h2(0.1f*acc1.x, 0.1f*acc1.y), f2h2(0.1f*acc1.z, 0.1f*acc1.w));
    n = n0 + tr * 4 + 2;
    if (n < N) bh2[(size_t)n * 16 + tc] =
        make_uint2(f2h2(0.1f*acc2.x, 0.1f*acc2.y), f2h2(0.1f*acc2.z, 0.1f*acc2.w));
    n = n0 + tr * 4 + 3;
    if (n < N) bh2[(size_t)n * 16 + tc] =
        make_uint2(f2h2(0.1f*acc3.x, 0.1f*acc3.y), f2h2(0.1f*acc3.z, 0.1f*acc3.w));
}

// ======== bucketed CSR build: 3 passes, XCD-local writes ========
// bucket = dst >> 8 (256 buckets cover dst < 65536)

__global__ __launch_bounds__(256) void bucketcnt_kernel(const int* __restrict__ ei,
                                                        int* __restrict__ gcnt, int E) {
    __shared__ int lh[256];
    lh[threadIdx.x] = 0;
    __syncthreads();
    for (int e = blockIdx.x * 256 + threadIdx.x; e < E; e += gridDim.x * 256)
        atomicAdd(&lh[ei[E + e] >> 8], 1);
    __syncthreads();
    if (lh[threadIdx.x]) atomicAdd(&gcnt[threadIdx.x], lh[threadIdx.x]);
}

__global__ __launch_bounds__(256) void bscan_kernel(const int* __restrict__ gcnt,
                                                    int* __restrict__ goff,
                                                    int* __restrict__ gcur) {
    __shared__ int sd[256];
    int t = threadIdx.x;
    int c = gcnt[t];
    sd[t] = c;
    __syncthreads();
    for (int o = 1; o < 256; o <<= 1) {
        int v = (t >= o) ? sd[t - o] : 0;
        __syncthreads();
        sd[t] += v;
        __syncthreads();
    }
    int ex = sd[t] - c;          // exclusive
    goff[t] = ex;
    gcur[t] = ex;
    if (t == 255) goff[256] = sd[255];
}

constexpr int CHUNK = 4096;      // 256 threads x 16 edges
__global__ __launch_bounds__(256) void bucketsct_kernel(const int* __restrict__ ei,
                                                        const float* __restrict__ ew,
                                                        int* __restrict__ gcur,
                                                        unsigned long long* __restrict__ tmp,
                                                        int E) {
    __shared__ int lh[256], lbase[256], lcur[256];
    const int t = threadIdx.x;
    const int e0 = blockIdx.x * CHUNK;
    lh[t] = 0;
    __syncthreads();
    int myd[16], mys[16];
    unsigned short myw[16];
#pragma unroll
    for (int k = 0; k < 16; ++k) {
        int e = e0 + k * 256 + t;
        if (e < E) {
            int d = ei[E + e];
            myd[k] = d; mys[k] = ei[e]; myw[k] = f2hbits(ew[e]);
            atomicAdd(&lh[d >> 8], 1);
        } else myd[k] = -1;
    }
    __syncthreads();
    if (lh[t]) lbase[t] = atomicAdd(&gcur[t], lh[t]);
    lcur[t] = 0;
    __syncthreads();
#pragma unroll
    for (int k = 0; k < 16; ++k) {
        if (myd[k] >= 0) {
            int bkt = myd[k] >> 8;
            int slot = atomicAdd(&lcur[bkt], 1);
            unsigned long long v = ((unsigned long long)(unsigned)myd[k] << 32)
                                 | ((unsigned long long)myw[k] << 16)
                                 | (unsigned)(mys[k] & 0xffff);
            tmp[(size_t)lbase[bkt] + slot] = v;
        }
    }
}

__global__ __launch_bounds__(256) void buildcsr_kernel(const unsigned long long* __restrict__ tmp,
                                                       const int* __restrict__ goff,
                                                       int* __restrict__ row_start,
                                                       unsigned* __restrict__ epk,
                                                       int N, int E) {
    __shared__ int cnt[256], sc[256], pos[256];
    const int b = blockIdx.x;
    const int t = threadIdx.x;
    const int lo = goff[b], hi = goff[b + 1];
    cnt[t] = 0;
    __syncthreads();
    for (int i = lo + t; i < hi; i += 256)
        atomicAdd(&cnt[(int)((tmp[i] >> 32) & 0xff)], 1);
    __syncthreads();
    sc[t] = cnt[t];
    __syncthreads();
    for (int o = 1; o < 256; o <<= 1) {
        int v = (t >= o) ? sc[t - o] : 0;
        __syncthreads();
        sc[t] += v;
        __syncthreads();
    }
    int excl = sc[t] - cnt[t];
    pos[t] = excl;
    int dst = b * 256 + t;
    if (dst < N) row_start[dst] = lo + excl;
    if (b == 0 && t == 0) row_start[N] = E;
    __syncthreads();
    for (int i = lo + t; i < hi; i += 256) {
        unsigned long long v = tmp[i];
        int dl = (int)((v >> 32) & 0xff);
        int p = atomicAdd(&pos[dl], 1);
        epk[lo + p] = (unsigned)(v & 0xffffffffu);
    }
}

// ---------------- one Peaceman-Rachford step (uh-only state) ----------------
// identity: 2*relu(u) - u = |u|  =>  uh = |u| - b ;  un = 2*V(uh) - uh - b
// normal:  s = V(uh_n);  un = 2s - uh_n - b;  out = fp16(|un| - b)
// first :  gather source = bh (uh_0 = -b):  s' = V(b);  un = -2s'
// last  :  out = fp16(relu(un))   (decoder input)
// layout: 16 lanes per node (lane owns 4 features = uint2), 4 nodes per wave.
// epk is chunk-loaded cooperatively (16 words in ONE coalesced load) and
// broadcast via __shfl(width 16) -> no per-edge global epk latency, and all
// 16 gather addresses of a chunk are available immediately (deep MLP).
__global__ __launch_bounds__(256) void step_kernel(const uint2* __restrict__ gh,  // gather rows [N*16]
                                                   const uint2* __restrict__ uhr, // own uh rows [N*16]
                                                   const uint2* __restrict__ bh,  // b rows [N*16]
                                                   const int* __restrict__ row_start,
                                                   const unsigned* __restrict__ epk,
                                                   uint2* __restrict__ outh,      // uh_next or relu(u)
                                                   int N, int is_first, int is_last) {
    const int wid  = threadIdx.x >> 6;
    const int lane = threadIdx.x & 63;
    const int fq   = lane & 15;                   // uint2 index within row
    const int node = (blockIdx.x * 4 + wid) * 4 + (lane >> 4);
    if (node >= N) return;
    const size_t r16 = (size_t)node * 16 + fq;

    // issue-early: own-row loads hide under the gather loop
    uint2 bvv = bh[r16];
    uint2 uvv = uhr[r16];

    const int e0 = row_start[node];
    const int e1 = row_start[node + 1];

    float a0[4] = {0,0,0,0}, a1[4] = {0,0,0,0};
    float a2[4] = {0,0,0,0}, a3[4] = {0,0,0,0};

    for (int base = e0; base < e1; base += 16) {
        int idx = base + fq;
        // cooperative chunk load: one coalesced 4B load covers 16 edges.
        // Out-of-range lanes get 0 -> weight 0, src 0 (harmless).
        unsigned p = (idx < e1) ? epk[idx] : 0u;
        const int cnt = min(16, e1 - base);
#pragma unroll
        for (int t0 = 0; t0 < 16; t0 += 4) {
            if (t0 >= cnt) break;
            unsigned p0 = __shfl(p, t0 + 0, 16);
            unsigned p1 = __shfl(p, t0 + 1, 16);
            unsigned p2 = __shfl(p, t0 + 2, 16);
            unsigned p3 = __shfl(p, t0 + 3, 16);
            uint2 v0 = gh[(size_t)(p0 & 0xffffu) * 16 + fq];
            uint2 v1 = gh[(size_t)(p1 & 0xffffu) * 16 + fq];
            uint2 v2 = gh[(size_t)(p2 & 0xffffu) * 16 + fq];
            uint2 v3 = gh[(size_t)(p3 & 0xffffu) * 16 + fq];
            fma4h(v0, hw(p0), a0);
            fma4h(v1, hw(p1), a1);
            fma4h(v2, hw(p2), a2);
            fma4h(v3, hw(p3), a3);
        }
    }
    float s[4];
#pragma unroll
    for (int i = 0; i < 4; ++i) s[i] = (a0[i] + a1[i]) + (a2[i] + a3[i]);

    float bf[4];
    unpack4(bvv, bf);
    float un[4];
    if (is_first) {
#pragma unroll
        for (int i = 0; i < 4; ++i) un[i] = -2.f * s[i];
    } else {
        float uhv[4];
        unpack4(uvv, uhv);
#pragma unroll
        for (int i = 0; i < 4; ++i) un[i] = 2.f * s[i] - uhv[i] - bf[i];
    }
    float ov[4];
    if (is_last) {
#pragma unroll
        for (int i = 0; i < 4; ++i) ov[i] = fmaxf(un[i], 0.f);
    } else {
#pragma unroll
        for (int i = 0; i < 4; ++i) ov[i] = fabsf(un[i]) - bf[i];
    }
    outh[r16] = make_uint2(f2h2(ov[0], ov[1]), f2h2(ov[2], ov[3]));
}

// ------------- out = rh @ W_dec, rh already relu'd fp16 (register-tiled 4x4) -------------
__global__ __launch_bounds__(256) void dec_kernel(const uint2* __restrict__ rh2,
                                                  const float* __restrict__ Wd,
                                                  float* __restrict__ out, int N) {
    __shared__ float xs[64][68];    // transposed rh chunk
    __shared__ float wls[64][64];
    const int t  = threadIdx.x;
    const int tr = t >> 4;
    const int tc = t & 15;
    const int n0 = blockIdx.x * 64;

    for (int i = t; i < 64 * 64 / 4; i += 256)
        reinterpret_cast<float4*>(&wls[0][0])[i] = reinterpret_cast<const float4*>(Wd)[i];
    // conflict-free staging: 16 simultaneous writers hit 16 consecutive rows
    for (int rp = 0; rp < 64; rp += 16) {
        int r = rp + (t & 15);
        int j = t >> 4;              // uint2 index 0..15
        int c = j * 4;
        int n = n0 + r; if (n >= N) n = N - 1;
        uint2 v = rh2[(size_t)n * 16 + j];
        float f[4];
        unpack4(v, f);
#pragma unroll
        for (int i = 0; i < 4; ++i) xs[c + i][r] = f[i];
    }
    __syncthreads();

    float4 acc0 = {0,0,0,0}, acc1 = {0,0,0,0}, acc2 = {0,0,0,0}, acc3 = {0,0,0,0};
#pragma unroll 8
    for (int k = 0; k < 64; ++k) {
        float4 xv = *reinterpret_cast<const float4*>(&xs[k][tr * 4]);
        float4 wv = *reinterpret_cast<const float4*>(&wls[k][tc * 4]);
        acc0.x = fmaf(xv.x, wv.x, acc0.x); acc0.y = fmaf(xv.x, wv.y, acc0.y);
        acc0.z = fmaf(xv.x, wv.z, acc0.z); acc0.w = fmaf(xv.x, wv.w, acc0.w);
        acc1.x = fmaf(xv.y, wv.x, acc1.x); acc1.y = fmaf(xv.y, wv.y, acc1.y);
        acc1.z = fmaf(xv.y, wv.z, acc1.z); acc1.w = fmaf(xv.y, wv.w, acc1.w);
        acc2.x = fmaf(xv.z, wv.x, acc2.x); acc2.y = fmaf(xv.z, wv.y, acc2.y);
        acc2.z = fmaf(xv.z, wv.z, acc2.z); acc2.w = fmaf(xv.z, wv.w, acc2.w);
        acc3.x = fmaf(xv.w, wv.x, acc3.x); acc3.y = fmaf(xv.w, wv.y, acc3.y);
        acc3.z = fmaf(xv.w, wv.z, acc3.z); acc3.w = fmaf(xv.w, wv.w, acc3.w);
    }
    int n;
    n = n0 + tr * 4 + 0;
    if (n < N) reinterpret_cast<float4*>(out + (size_t)n * 64)[tc] = acc0;
    n = n0 + tr * 4 + 1;
    if (n < N) reinterpret_cast<float4*>(out + (size_t)n * 64)[tc] = acc1;
    n = n0 + tr * 4 + 2;
    if (n < N) reinterpret_cast<float4*>(out + (size_t)n * 64)[tc] = acc2;
    n = n0 + tr * 4 + 3;
    if (n < N) reinterpret_cast<float4*>(out + (size_t)n * 64)[tc] = acc3;
}

extern "C" void kernel_launch(void* const* d_in, const int* in_sizes, int n_in,
                              void* d_out, int out_size, void* d_ws, size_t ws_size,
                              hipStream_t stream) {
    const float* x  = (const float*)d_in[0];
    const int*   ei = (const int*)d_in[1];
    const float* ew = (const float*)d_in[2];
    const float* We = (const float*)d_in[3];
    const float* Wb = (const float*)d_in[4];
    const float* Wd = (const float*)d_in[5];
    float* out = (float*)d_out;

    const int N = in_sizes[0] / FIN;
    const int E = in_sizes[2];

    char* ws = (char*)d_ws;
    size_t off = 0;
    auto alloc = [&](size_t bytes) -> void* {
        void* p = ws + off;
        off = (off + bytes + 255) & ~(size_t)255;
        return p;
    };
    const size_t nodef16 = (size_t)N * H * sizeof(unsigned short);
    unsigned short* bh   = (unsigned short*)alloc(nodef16);
    unsigned short* uhha = (unsigned short*)alloc(nodef16);
    unsigned short* uhhb = (unsigned short*)alloc(nodef16);
    float* Wc   = (float*)alloc((size_t)FIN * H * sizeof(float));
    int*   rsrt = (int*)alloc((size_t)(N + 1) * sizeof(int));
    int*   gcnt = (int*)alloc(256 * sizeof(int));
    int*   goff = (int*)alloc(257 * sizeof(int));
    int*   gcur = (int*)alloc(256 * sizeof(int));
    unsigned long long* tmp = (unsigned long long*)alloc((size_t)E * sizeof(unsigned long long));
    unsigned* epk = (unsigned*)alloc((size_t)E * sizeof(unsigned));

    // ---- CSR build (bucketed counting sort) ----
    hipMemsetAsync(gcnt, 0, 256 * sizeof(int), stream);
    bucketcnt_kernel<<<256, 256, 0, stream>>>(ei, gcnt, E);
    bscan_kernel<<<1, 256, 0, stream>>>(gcnt, goff, gcur);
    bucketsct_kernel<<<(E + CHUNK - 1) / CHUNK, 256, 0, stream>>>(ei, ew, gcur, tmp, E);
    const int nbk = (N + 255) >> 8;
    buildcsr_kernel<<<nbk, 256, 0, stream>>>(tmp, goff, rsrt, epk, N, E);

    // ---- encoder path: only b (fp16) is materialized ----
    wc_kernel<<<FIN * H / 256, 256, 0, stream>>>(We, Wb, Wc);
    benc_kernel<<<(N + 63) / 64, 256, 0, stream>>>(x, Wc, bh, N);

    const int sgrid = (N + 15) / 16;   // 16 nodes per block (4 waves x 4 nodes)
    // first step: uh_0 = -b handled by gathering bh with sign flip
    step_kernel<<<sgrid, 256, 0, stream>>>((const uint2*)bh, (const uint2*)bh, (const uint2*)bh,
                                           rsrt, epk, (uint2*)uhha, N, 1, 0);
    unsigned short *uhcur = uhha, *uhnext = uhhb;
    for (int it = 1; it < NIT; ++it) {
        int last = (it == NIT - 1) ? 1 : 0;
        step_kernel<<<sgrid, 256, 0, stream>>>((const uint2*)uhcur, (const uint2*)uhcur,
                                               (const uint2*)bh, rsrt, epk,
                                               (uint2*)uhnext, N, 0, last);
        unsigned short* th;
        th = uhcur; uhcur = uhnext; uhnext = th;
    }

    // uhcur now holds fp16 relu(u_20)
    dec_kernel<<<(N + 63) / 64, 256, 0, stream>>>((const uint2*)uhcur, Wd, out, N);
}